// Round 2
// baseline (439.483 us; speedup 1.0000x reference)
//
#include <hip/hip_runtime.h>
#include <cstdint>

typedef unsigned short u16;
typedef __bf16 bf16x8 __attribute__((ext_vector_type(8)));
typedef float f32x4 __attribute__((ext_vector_type(4)));

#define LN_EPS 1e-5f
#define SCALE_Q 0.17677669529663689f  // 32^-0.5

__device__ __forceinline__ u16 f2bf(float f) {
    union { float f; unsigned int i; } c; c.f = f;
    unsigned int r = c.i + 0x7FFFu + ((c.i >> 16) & 1u);
    return (u16)(r >> 16);
}
// async global->LDS, 16B per lane; lds pointer must be wave-uniform
__device__ __forceinline__ void async16(const void* g, void* l) {
    __builtin_amdgcn_global_load_lds(
        (__attribute__((address_space(1))) unsigned int*)(unsigned long long)g,
        (__attribute__((address_space(3))) unsigned int*)l, 16, 0, 0);
}

// ------------- weight transpose + bf16 cast: Out[c*R + r] = bf16(In[r*C + c]) -------------
__global__ void transpose_k(const float* __restrict__ In, u16* __restrict__ Out, int R, int C) {
    __shared__ float tile[32][33];
    const int bx = blockIdx.x * 32, by = blockIdx.y * 32;
    const int tx = threadIdx.x, ty = threadIdx.y;
    for (int i = 0; i < 32; i += 8)
        tile[ty + i][tx] = In[(size_t)(by + ty + i) * C + bx + tx];
    __syncthreads();
    for (int i = 0; i < 32; i += 8)
        Out[(size_t)(bx + ty + i) * R + by + tx] = f2bf(tile[tx][ty + i]);
}

// ------------- LayerNorm: one wave per token (C=256); fp32 in -> bf16 out -------------
__global__ __launch_bounds__(256) void ln_k(const float* __restrict__ X, const float* __restrict__ G,
                                            const float* __restrict__ Bt, u16* __restrict__ Y) {
    const int token = blockIdx.x * 4 + (threadIdx.x >> 6);
    const int ln = threadIdx.x & 63;
    const float4 rv = *(const float4*)(X + (size_t)token * 256 + ln * 4);
    float s = rv.x + rv.y + rv.z + rv.w;
    float q = rv.x * rv.x + rv.y * rv.y + rv.z * rv.z + rv.w * rv.w;
    #pragma unroll
    for (int m = 1; m < 64; m <<= 1) { s += __shfl_xor(s, m, 64); q += __shfl_xor(q, m, 64); }
    const float mean = s * (1.f / 256.f);
    const float var  = q * (1.f / 256.f) - mean * mean;
    const float rs   = rsqrtf(var + LN_EPS);
    const float4 gv = *(const float4*)(G + ln * 4);
    const float4 bv = *(const float4*)(Bt + ln * 4);
    ushort4 o;
    o.x = f2bf((rv.x - mean) * rs * gv.x + bv.x);
    o.y = f2bf((rv.y - mean) * rs * gv.y + bv.y);
    o.z = f2bf((rv.z - mean) * rs * gv.z + bv.z);
    o.w = f2bf((rv.w - mean) * rs * gv.w + bv.w);
    *(ushort4*)(Y + (size_t)token * 256 + ln * 4) = o;
}

// ------------- GEMM (B^T form): Y[m,n] = sum_k X[m,k]*Wt[n,k] + epilogue -------------
// mode: 0 = +bias ; 1 = (+bias)*scale ; 2 = +bias + Res[m,n] ; 3 = gelu(+bias)
// writes fp32 to Yf if non-null, else bf16 to Ybf.
__global__ __launch_bounds__(256, 2) void gemm_bt(
    const u16* __restrict__ X, const u16* __restrict__ Wt,
    const float* __restrict__ Bias, const float* __restrict__ Res,
    u16* __restrict__ Ybf, float* __restrict__ Yf,
    int M, int N, int K, int mode, float scale) {
    __shared__ alignas(16) u16 sA[128 * 64];
    __shared__ alignas(16) u16 sB[128 * 64];
    const int tid = threadIdx.x, wv = tid >> 6, ln = tid & 63;
    const int quad = ln >> 4, l16 = ln & 15;
    const int m0 = blockIdx.y * 128, n0 = blockIdx.x * 128;
    const int mw = (wv >> 1) * 64, nw = (wv & 1) * 64;
    const int r8 = ln >> 3, c8 = ln & 7;
    const f32x4 z4 = {0.f, 0.f, 0.f, 0.f};
    f32x4 acc[4][4];
    #pragma unroll
    for (int i = 0; i < 4; i++)
        #pragma unroll
        for (int j = 0; j < 4; j++) acc[i][j] = z4;

    for (int k0 = 0; k0 < K; k0 += 64) {
        __syncthreads();
        #pragma unroll
        for (int i = 0; i < 4; i++) {
            const int row = wv * 32 + i * 8;
            async16(X  + (size_t)(m0 + row + r8) * K + k0 + c8 * 8, &sA[row * 64]);
            async16(Wt + (size_t)(n0 + row + r8) * K + k0 + c8 * 8, &sB[row * 64]);
        }
        __syncthreads();
        #pragma unroll
        for (int kk = 0; kk < 2; kk++) {
            bf16x8 af[4], bfr[4];
            #pragma unroll
            for (int i = 0; i < 4; i++) af[i]  = *(const bf16x8*)&sA[(mw + i * 16 + l16) * 64 + kk * 32 + quad * 8];
            #pragma unroll
            for (int j = 0; j < 4; j++) bfr[j] = *(const bf16x8*)&sB[(nw + j * 16 + l16) * 64 + kk * 32 + quad * 8];
            #pragma unroll
            for (int i = 0; i < 4; i++)
                #pragma unroll
                for (int j = 0; j < 4; j++)
                    acc[i][j] = __builtin_amdgcn_mfma_f32_16x16x32_bf16(af[i], bfr[j], acc[i][j], 0, 0, 0);
        }
    }
    #pragma unroll
    for (int j = 0; j < 4; j++) {
        const int col = n0 + nw + j * 16 + l16;
        const float bc = Bias[col];
        #pragma unroll
        for (int i = 0; i < 4; i++) {
            #pragma unroll
            for (int r = 0; r < 4; r++) {
                const int row = m0 + mw + i * 16 + quad * 4 + r;
                float v = acc[i][j][r] + bc;
                if (mode == 1) v *= scale;
                else if (mode == 2) v += Res[(size_t)row * N + col];
                else if (mode == 3) v = 0.5f * v * (1.f + erff(v * 0.70710678118654752f));
                if (Yf) Yf[(size_t)row * N + col] = v;
                else    Ybf[(size_t)row * N + col] = f2bf(v);
            }
        }
    }
}

// ------------- windowed attention, one block per (window, head) -------------
// T=128 tokens, HD=32. Scores in regs (C/D layout), bias computed on the fly,
// softmax over lane&15 groups, P through LDS into A-layout for P·V.
__global__ __launch_bounds__(256, 2) void attn_k(
    const u16* __restrict__ Qb, const u16* __restrict__ Kb, const u16* __restrict__ Vb,
    const float* __restrict__ pos, const float* __restrict__ pw1, const float* __restrict__ pb1,
    const float* __restrict__ bng, const float* __restrict__ bnb, const float* __restrict__ bnm,
    const float* __restrict__ bnv, const float* __restrict__ pw2,
    u16* __restrict__ Ob) {
    constexpr int SPS = 136;  // sP row stride (bf16): 16B-aligned rows, breaks pow2 banks
    __shared__ alignas(16) u16 sQ[128 * 32];
    __shared__ alignas(16) u16 sK[128 * 32];
    __shared__ alignas(16) u16 sVt[32 * 128];
    __shared__ alignas(16) u16 sP[128 * SPS];
    __shared__ float sTa[16 * 128];
    __shared__ float sTa2[16 * 128];
    __shared__ float sPw2[16];

    const int n = blockIdx.x, h = blockIdx.y;
    const int tid = threadIdx.x, wv = tid >> 6, ln = tid & 63;
    const int quad = ln >> 4, l16 = ln & 15;
    const int wh = n >> 4, ww = n & 15;

    // stage Q,K via async16 (layout [t][32]); V transposed manually into [d][t]
    {
        const int tb = wv * 16 + (ln >> 2);
        const int d8 = ln & 3;
        #pragma unroll
        for (int i = 0; i < 2; i++) {
            const int tt = tb + i * 64;
            const int l = (wh * 4 + (tt >> 5)) * 512 + ww * 32 + (tt & 31);
            const size_t g = (size_t)l * 256 + h * 32 + d8 * 8;
            async16(Qb + g, &sQ[(wv * 16 + i * 64) * 32]);
            async16(Kb + g, &sK[(wv * 16 + i * 64) * 32]);
        }
        #pragma unroll
        for (int i = 0; i < 2; i++) {
            const int tt = tb + i * 64;
            const int l = (wh * 4 + (tt >> 5)) * 512 + ww * 32 + (tt & 31);
            const uint4 raw = *(const uint4*)(Vb + (size_t)l * 256 + h * 32 + d8 * 8);
            const u16* e = (const u16*)&raw;
            #pragma unroll
            for (int j = 0; j < 8; j++) sVt[(d8 * 8 + j) * 128 + tt] = e[j];
        }
    }
    // per-window bias tables: bias_pre[o,t,u] = ta2[o][t] - ta[o][u]
    #pragma unroll
    for (int r = 0; r < 8; r++) {
        const int e = tid + r * 256;
        const int o = e >> 7, t = e & 127;
        const int l = (wh * 4 + (t >> 5)) * 512 + ww * 32 + (t & 31);
        const float px = pos[l * 2], py = pos[l * 2 + 1];
        const float sv = rsqrtf(bnv[o] + LN_EPS) * bng[o];
        const float ta = sv * (pw1[o * 2] * px + pw1[o * 2 + 1] * py);
        const float ct = (pb1[o] - bnm[o]) * sv + bnb[o];
        sTa[o * 128 + t] = ta;
        sTa2[o * 128 + t] = ta + ct;
    }
    if (tid < 16) sPw2[tid] = pw2[h * 16 + tid];
    __syncthreads();

    // S = Q K^T (Q pre-scaled in projection). acc[i][j]: row t=wv*32+i*16+quad*4+r, col u=j*16+l16
    const f32x4 z4 = {0.f, 0.f, 0.f, 0.f};
    f32x4 acc[2][8];
    {
        bf16x8 qf[2], kf[8];
        #pragma unroll
        for (int i = 0; i < 2; i++) qf[i] = *(const bf16x8*)&sQ[(wv * 32 + i * 16 + l16) * 32 + quad * 8];
        #pragma unroll
        for (int j = 0; j < 8; j++) kf[j] = *(const bf16x8*)&sK[(j * 16 + l16) * 32 + quad * 8];
        #pragma unroll
        for (int i = 0; i < 2; i++)
            #pragma unroll
            for (int j = 0; j < 8; j++)
                acc[i][j] = __builtin_amdgcn_mfma_f32_16x16x32_bf16(qf[i], kf[j], z4, 0, 0, 0);
    }
    // bias (pb2[h] is row-constant over u -> cancels in softmax, omitted)
    for (int o = 0; o < 16; o++) {
        const float w2 = sPw2[o];
        float t2[8], uo[8];
        #pragma unroll
        for (int i = 0; i < 2; i++)
            #pragma unroll
            for (int r = 0; r < 4; r++)
                t2[i * 4 + r] = sTa2[o * 128 + wv * 32 + i * 16 + quad * 4 + r];
        #pragma unroll
        for (int j = 0; j < 8; j++) uo[j] = sTa[o * 128 + j * 16 + l16];
        #pragma unroll
        for (int i = 0; i < 2; i++)
            #pragma unroll
            for (int j = 0; j < 8; j++)
                #pragma unroll
                for (int r = 0; r < 4; r++)
                    acc[i][j][r] += w2 * fmaxf(t2[i * 4 + r] - uo[j], 0.f);
    }
    // softmax over u: reduce over j in regs, then over l16 via shfl_xor (masks 1,2,4,8)
    float rinv[2][4];
    #pragma unroll
    for (int i = 0; i < 2; i++) {
        #pragma unroll
        for (int r = 0; r < 4; r++) {
            float mx = acc[i][0][r];
            #pragma unroll
            for (int j = 1; j < 8; j++) mx = fmaxf(mx, acc[i][j][r]);
            #pragma unroll
            for (int m = 1; m < 16; m <<= 1) mx = fmaxf(mx, __shfl_xor(mx, m, 64));
            float sm = 0.f;
            #pragma unroll
            for (int j = 0; j < 8; j++) {
                const float p = __expf(acc[i][j][r] - mx);
                acc[i][j][r] = p;
                sm += p;
            }
            #pragma unroll
            for (int m = 1; m < 16; m <<= 1) sm += __shfl_xor(sm, m, 64);
            rinv[i][r] = 1.f / sm;
        }
    }
    // P -> LDS (bf16, unnormalized)
    #pragma unroll
    for (int i = 0; i < 2; i++)
        #pragma unroll
        for (int j = 0; j < 8; j++)
            #pragma unroll
            for (int r = 0; r < 4; r++) {
                const int t = wv * 32 + i * 16 + quad * 4 + r;
                const int u = j * 16 + l16;
                sP[t * SPS + u] = f2bf(acc[i][j][r]);
            }
    __syncthreads();
    // O = P V  (A-frag from sP, B-frag from sVt[d][u])
    f32x4 oacc[2][2];
    #pragma unroll
    for (int i = 0; i < 2; i++)
        #pragma unroll
        for (int jd = 0; jd < 2; jd++) oacc[i][jd] = z4;
    #pragma unroll
    for (int ku = 0; ku < 4; ku++) {
        bf16x8 pf[2], vf[2];
        #pragma unroll
        for (int i = 0; i < 2; i++) pf[i] = *(const bf16x8*)&sP[(wv * 32 + i * 16 + l16) * SPS + ku * 32 + quad * 8];
        #pragma unroll
        for (int jd = 0; jd < 2; jd++) vf[jd] = *(const bf16x8*)&sVt[(jd * 16 + l16) * 128 + ku * 32 + quad * 8];
        #pragma unroll
        for (int i = 0; i < 2; i++)
            #pragma unroll
            for (int jd = 0; jd < 2; jd++)
                oacc[i][jd] = __builtin_amdgcn_mfma_f32_16x16x32_bf16(pf[i], vf[jd], oacc[i][jd], 0, 0, 0);
    }
    #pragma unroll
    for (int i = 0; i < 2; i++)
        #pragma unroll
        for (int jd = 0; jd < 2; jd++)
            #pragma unroll
            for (int r = 0; r < 4; r++) {
                const int t = wv * 32 + i * 16 + quad * 4 + r;
                const int d = jd * 16 + l16;
                const int l = (wh * 4 + (t >> 5)) * 512 + ww * 32 + (t & 31);
                Ob[(size_t)l * 256 + h * 32 + d] = f2bf(oacc[i][jd][r] * rinv[i][r]);
            }
}

extern "C" void kernel_launch(void* const* d_in, const int* in_sizes, int n_in,
                              void* d_out, int out_size, void* d_ws, size_t ws_size,
                              hipStream_t stream) {
    const float* x    = (const float*)d_in[0];
    const float* pos  = (const float*)d_in[1];
    const float* n1g  = (const float*)d_in[2];
    const float* n1b  = (const float*)d_in[3];
    const float* wq   = (const float*)d_in[4];
    const float* bq   = (const float*)d_in[5];
    const float* wk   = (const float*)d_in[6];
    const float* bk   = (const float*)d_in[7];
    const float* wvw  = (const float*)d_in[8];
    const float* bv   = (const float*)d_in[9];
    const float* wo   = (const float*)d_in[10];
    const float* bo   = (const float*)d_in[11];
    const float* n2g  = (const float*)d_in[12];
    const float* n2b  = (const float*)d_in[13];
    const float* wfc1 = (const float*)d_in[14];
    const float* bfc1 = (const float*)d_in[15];
    const float* wfc2 = (const float*)d_in[16];
    const float* bfc2 = (const float*)d_in[17];
    const float* pw1  = (const float*)d_in[18];
    const float* pb1  = (const float*)d_in[19];
    const float* bng  = (const float*)d_in[20];
    const float* bnb  = (const float*)d_in[21];
    const float* bnm  = (const float*)d_in[22];
    const float* bnv  = (const float*)d_in[23];
    const float* pw2  = (const float*)d_in[24];
    float* out = (float*)d_out;
    u16* ws  = (u16*)d_ws;

    const size_t SZ = (size_t)32768 * 256;  // one [L,C] bf16 slot
    u16* s0 = ws;            // xn, then O
    u16* s1 = ws + SZ;       // Q, then xn2
    u16* s2 = ws + 2 * SZ;   // K, then H (chunk, spans s2..s3)
    u16* s3 = ws + 3 * SZ;   // V
    u16* wqT  = ws + 4 * SZ;
    u16* wkT  = wqT + 65536;
    u16* wvT  = wkT + 65536;
    u16* woT  = wvT + 65536;
    u16* fc1T = woT + 65536;
    u16* fc2T = fc1T + 262144;

    dim3 tb(32, 8);
    transpose_k<<<dim3(8, 8),  tb, 0, stream>>>(wq,   wqT,  256,  256);
    transpose_k<<<dim3(8, 8),  tb, 0, stream>>>(wk,   wkT,  256,  256);
    transpose_k<<<dim3(8, 8),  tb, 0, stream>>>(wvw,  wvT,  256,  256);
    transpose_k<<<dim3(8, 8),  tb, 0, stream>>>(wo,   woT,  256,  256);
    transpose_k<<<dim3(32, 8), tb, 0, stream>>>(wfc1, fc1T, 256,  1024);
    transpose_k<<<dim3(8, 32), tb, 0, stream>>>(wfc2, fc2T, 1024, 256);

    ln_k<<<8192, 256, 0, stream>>>(x, n1g, n1b, s0);

    gemm_bt<<<dim3(2, 256), 256, 0, stream>>>(s0, wqT, bq, nullptr, s1, nullptr, 32768, 256, 256, 1, SCALE_Q);
    gemm_bt<<<dim3(2, 256), 256, 0, stream>>>(s0, wkT, bk, nullptr, s2, nullptr, 32768, 256, 256, 0, 1.f);
    gemm_bt<<<dim3(2, 256), 256, 0, stream>>>(s0, wvT, bv, nullptr, s3, nullptr, 32768, 256, 256, 0, 1.f);

    attn_k<<<dim3(256, 8), 256, 0, stream>>>(s1, s2, s3, pos, pw1, pb1, bng, bnb, bnm, bnv, pw2, s0);

    // X1 = x + O@wo + bo  -> lives in d_out (fp32)
    gemm_bt<<<dim3(2, 256), 256, 0, stream>>>(s0, woT, bo, x, nullptr, out, 32768, 256, 256, 2, 1.f);

    ln_k<<<8192, 256, 0, stream>>>(out, n2g, n2b, s1);

    // MLP in 2 row-chunks so H (16384x1024 bf16) fits in slots s2..s3
    for (int c = 0; c < 2; c++) {
        const size_t ro = (size_t)c * 16384;
        gemm_bt<<<dim3(8, 128), 256, 0, stream>>>(s1 + ro * 256, fc1T, bfc1, nullptr, s2, nullptr, 16384, 1024, 256, 3, 1.f);
        gemm_bt<<<dim3(2, 128), 256, 0, stream>>>(s2, fc2T, bfc2, out + ro * 256, nullptr, out + ro * 256, 16384, 256, 1024, 2, 1.f);
    }
}

// Round 3
// 434.638 us; speedup vs baseline: 1.0111x; 1.0111x over previous
//
#include <hip/hip_runtime.h>
#include <cstdint>

typedef unsigned short u16;
typedef __bf16 bf16x8 __attribute__((ext_vector_type(8)));
typedef float f32x4 __attribute__((ext_vector_type(4)));

#define LN_EPS 1e-5f
#define SCALE_Q 0.17677669529663689f  // 32^-0.5

__device__ __forceinline__ u16 f2bf(float f) {
    union { float f; unsigned int i; } c; c.f = f;
    unsigned int r = c.i + 0x7FFFu + ((c.i >> 16) & 1u);
    return (u16)(r >> 16);
}
// pack two f32 -> two bf16 (truncation) in one v_perm_b32
__device__ __forceinline__ unsigned pack2(float hi, float lo) {
    return __builtin_amdgcn_perm(__float_as_uint(hi), __float_as_uint(lo), 0x07060302u);
}
// async global->LDS, 16B per lane; lds pointer must be wave-uniform
__device__ __forceinline__ void async16(const void* g, void* l) {
    __builtin_amdgcn_global_load_lds(
        (__attribute__((address_space(1))) unsigned int*)(unsigned long long)g,
        (__attribute__((address_space(3))) unsigned int*)l, 16, 0, 0);
}

// ------------- all 6 weight transposes (+bf16 cast) in one dispatch -------------
__global__ void transpose_all(const float* __restrict__ wq, const float* __restrict__ wk,
                              const float* __restrict__ wv, const float* __restrict__ wo,
                              const float* __restrict__ f1, const float* __restrict__ f2,
                              u16* oq, u16* ok, u16* ov, u16* oo, u16* o1, u16* o2) {
    __shared__ float tile[32][33];
    const int b = blockIdx.x;
    const float* In; u16* Out; int R, C, bx, by;
    if (b < 256) {
        const int m = b >> 6, l = b & 63;
        In = m == 0 ? wq : (m == 1 ? wk : (m == 2 ? wv : wo));
        Out = m == 0 ? oq : (m == 1 ? ok : (m == 2 ? ov : oo));
        R = 256; C = 256; bx = (l & 7) * 32; by = (l >> 3) * 32;
    } else if (b < 512) {
        const int l = b - 256; In = f1; Out = o1; R = 256; C = 1024;
        bx = (l & 31) * 32; by = (l >> 5) * 32;
    } else {
        const int l = b - 512; In = f2; Out = o2; R = 1024; C = 256;
        bx = (l & 7) * 32; by = (l >> 3) * 32;
    }
    const int tx = threadIdx.x, ty = threadIdx.y;
    for (int i = 0; i < 32; i += 8)
        tile[ty + i][tx] = In[(size_t)(by + ty + i) * C + bx + tx];
    __syncthreads();
    for (int i = 0; i < 32; i += 8)
        Out[(size_t)(bx + ty + i) * R + by + tx] = f2bf(tile[tx][ty + i]);
}

// ------------- LayerNorm: one wave per token (C=256); fp32 in -> bf16 out -------------
__global__ __launch_bounds__(256) void ln_k(const float* __restrict__ X, const float* __restrict__ G,
                                            const float* __restrict__ Bt, u16* __restrict__ Y) {
    const int token = blockIdx.x * 4 + (threadIdx.x >> 6);
    const int ln = threadIdx.x & 63;
    const float4 rv = *(const float4*)(X + (size_t)token * 256 + ln * 4);
    float s = rv.x + rv.y + rv.z + rv.w;
    float q = rv.x * rv.x + rv.y * rv.y + rv.z * rv.z + rv.w * rv.w;
    #pragma unroll
    for (int m = 1; m < 64; m <<= 1) { s += __shfl_xor(s, m, 64); q += __shfl_xor(q, m, 64); }
    const float mean = s * (1.f / 256.f);
    const float var  = q * (1.f / 256.f) - mean * mean;
    const float rs   = rsqrtf(var + LN_EPS);
    const float4 gv = *(const float4*)(G + ln * 4);
    const float4 bv = *(const float4*)(Bt + ln * 4);
    ushort4 o;
    o.x = f2bf((rv.x - mean) * rs * gv.x + bv.x);
    o.y = f2bf((rv.y - mean) * rs * gv.y + bv.y);
    o.z = f2bf((rv.z - mean) * rs * gv.z + bv.z);
    o.w = f2bf((rv.w - mean) * rs * gv.w + bv.w);
    *(ushort4*)(Y + (size_t)token * 256 + ln * 4) = o;
}

// ------------- GEMM (B^T form): Y[m,n] = sum_k X[m,k]*Wt[n,k] + epilogue -------------
// mode: 0 = +bias ; 2 = +bias + Res[m,n] ; 3 = gelu(+bias) ; 4 = fused-QKV (seg bias, Q scaled)
__global__ __launch_bounds__(256, 2) void gemm_bt(
    const u16* __restrict__ X, const u16* __restrict__ Wt,
    const float* __restrict__ B1, const float* __restrict__ B2, const float* __restrict__ B3,
    const float* __restrict__ Res,
    u16* __restrict__ Ybf, float* __restrict__ Yf,
    int M, int N, int K, int mode) {
    __shared__ alignas(16) u16 sA[128 * 64];
    __shared__ alignas(16) u16 sB[128 * 64];
    const int tid = threadIdx.x, wv = tid >> 6, ln = tid & 63;
    const int quad = ln >> 4, l16 = ln & 15;
    const int m0 = blockIdx.y * 128, n0 = blockIdx.x * 128;
    const int mw = (wv >> 1) * 64, nw = (wv & 1) * 64;
    const int r8 = ln >> 3, c8 = ln & 7;
    const f32x4 z4 = {0.f, 0.f, 0.f, 0.f};
    f32x4 acc[4][4];
    #pragma unroll
    for (int i = 0; i < 4; i++)
        #pragma unroll
        for (int j = 0; j < 4; j++) acc[i][j] = z4;

    for (int k0 = 0; k0 < K; k0 += 64) {
        __syncthreads();
        #pragma unroll
        for (int i = 0; i < 4; i++) {
            const int row = wv * 32 + i * 8;
            async16(X  + (size_t)(m0 + row + r8) * K + k0 + c8 * 8, &sA[row * 64]);
            async16(Wt + (size_t)(n0 + row + r8) * K + k0 + c8 * 8, &sB[row * 64]);
        }
        __syncthreads();
        #pragma unroll
        for (int kk = 0; kk < 2; kk++) {
            bf16x8 af[4], bfr[4];
            #pragma unroll
            for (int i = 0; i < 4; i++) af[i]  = *(const bf16x8*)&sA[(mw + i * 16 + l16) * 64 + kk * 32 + quad * 8];
            #pragma unroll
            for (int j = 0; j < 4; j++) bfr[j] = *(const bf16x8*)&sB[(nw + j * 16 + l16) * 64 + kk * 32 + quad * 8];
            #pragma unroll
            for (int i = 0; i < 4; i++)
                #pragma unroll
                for (int j = 0; j < 4; j++)
                    acc[i][j] = __builtin_amdgcn_mfma_f32_16x16x32_bf16(af[i], bfr[j], acc[i][j], 0, 0, 0);
        }
    }
    // epilogue
    const int seg = n0 >> 8;  // for mode 4 (block fully inside one 256-col segment)
    const float* bp = (mode == 4) ? (seg == 0 ? B1 : (seg == 1 ? B2 : B3)) : B1;
    const float sc = (mode == 4 && seg == 0) ? SCALE_Q : 1.f;
    #pragma unroll
    for (int j = 0; j < 4; j++) {
        const int col = n0 + nw + j * 16 + l16;
        const float bc = bp[mode == 4 ? (col & 255) : col];
        #pragma unroll
        for (int i = 0; i < 4; i++) {
            #pragma unroll
            for (int r = 0; r < 4; r++) {
                const int row = m0 + mw + i * 16 + quad * 4 + r;
                float v = acc[i][j][r] + bc;
                if (mode == 4) v *= sc;
                else if (mode == 2) v += Res[(size_t)row * N + col];
                else if (mode == 3) {
                    // gelu(v) ~ v * sigmoid(1.5957691216*(v + 0.044715 v^3))
                    const float p = v * v;
                    const float qq = fmaf(p, -0.07135481283f, -1.5957691216f);
                    v = v / (1.f + __expf(v * qq));
                }
                if (Yf) Yf[(size_t)row * N + col] = v;
                else    Ybf[(size_t)row * N + col] = f2bf(v);
            }
        }
    }
}

// ------------- per-window bias: bias[h][t][u] = sum_o pw2[h][o]*relu(ta2[o][t]-ta[o][u]) -------------
// One block per window. Contraction over o via one 16x16x32 MFMA per (t, u-chunk):
// A[m=h][k=o] = pw2 (zero-padded 16x32), B[n=u][k=o] = relu-tensor built in-register (bf16 trunc).
__global__ __launch_bounds__(256) void bias_k(
    const float* __restrict__ pos, const float* __restrict__ pw1, const float* __restrict__ pb1,
    const float* __restrict__ bng, const float* __restrict__ bnb, const float* __restrict__ bnm,
    const float* __restrict__ bnv, const float* __restrict__ pw2, u16* __restrict__ Bg) {
    __shared__ float sTa[32 * 128], sTa2[32 * 128];  // o padded 16->32 with zeros
    __shared__ u16 sW[16 * 32];
    const int n = blockIdx.x, wh = n >> 4, ww = n & 15;
    const int tid = threadIdx.x, wv = tid >> 6, ln = tid & 63;
    const int quad = ln >> 4, l16 = ln & 15;
    for (int r = 0; r < 16; r++) {
        const int e = tid + r * 256, o = e >> 7, t = e & 127;
        float ta = 0.f, ta2 = 0.f;
        if (o < 16) {
            const int l = (wh * 4 + (t >> 5)) * 512 + ww * 32 + (t & 31);
            const float sv = rsqrtf(bnv[o] + LN_EPS) * bng[o];
            ta = sv * (pw1[o * 2] * pos[l * 2] + pw1[o * 2 + 1] * pos[l * 2 + 1]);
            ta2 = ta + (pb1[o] - bnm[o]) * sv + bnb[o];
        }
        sTa[o * 128 + t] = ta; sTa2[o * 128 + t] = ta2;
    }
    for (int r = 0; r < 2; r++) {
        const int e = tid + r * 256, h = e >> 5, o = e & 31;
        sW[e] = (h < 8 && o < 16) ? f2bf(pw2[h * 16 + o]) : (u16)0;
    }
    __syncthreads();
    const bf16x8 af = *(const bf16x8*)&sW[l16 * 32 + quad * 8];
    float uo[8][8];
    #pragma unroll
    for (int c = 0; c < 8; c++)
        #pragma unroll
        for (int j = 0; j < 8; j++)
            uo[c][j] = sTa[(quad * 8 + j) * 128 + c * 16 + l16];
    const f32x4 z4 = {0.f, 0.f, 0.f, 0.f};
    u16* outb = Bg + (size_t)n * 131072;  // 8*128*128
    for (int tl = 0; tl < 32; tl++) {
        const int t = wv * 32 + tl;
        float t2[8];
        #pragma unroll
        for (int j = 0; j < 8; j++) t2[j] = sTa2[(quad * 8 + j) * 128 + t];
        #pragma unroll
        for (int c = 0; c < 8; c++) {
            float rl[8];
            #pragma unroll
            for (int j = 0; j < 8; j++) rl[j] = fmaxf(t2[j] - uo[c][j], 0.f);
            union { unsigned u[4]; bf16x8 v; } bb;
            #pragma unroll
            for (int p = 0; p < 4; p++) bb.u[p] = pack2(rl[2 * p + 1], rl[2 * p]);
            const f32x4 cc = __builtin_amdgcn_mfma_f32_16x16x32_bf16(af, bb.v, z4, 0, 0, 0);
            if (quad < 2) {
                #pragma unroll
                for (int r = 0; r < 4; r++) {
                    const int h = quad * 4 + r;
                    outb[(size_t)h * 16384 + t * 128 + c * 16 + l16] =
                        (u16)(__float_as_uint(cc[r]) >> 16);
                }
            }
        }
    }
}

// ------------- windowed attention, one block per (window, head) -------------
// Bias is precomputed (bias_k); staged tile added to S in C/D layout.
__global__ __launch_bounds__(256, 2) void attn_k(
    const u16* __restrict__ Qkv, const u16* __restrict__ Bg, u16* __restrict__ Ob) {
    constexpr int SPS = 136;
    __shared__ alignas(16) u16 sQ[128 * 32];
    __shared__ alignas(16) u16 sK[128 * 32];
    __shared__ alignas(16) u16 sVt[32 * 128];
    __shared__ alignas(16) u16 sPB[128 * SPS];  // bias tile (stride 128), then P (stride 136)

    const int n = blockIdx.x, h = blockIdx.y;
    const int tid = threadIdx.x, wv = tid >> 6, ln = tid & 63;
    const int quad = ln >> 4, l16 = ln & 15;
    const int wh = n >> 4, ww = n & 15;

    // stage Q,K,bias via async16; V transposed manually into [d][t]
    {
        const int tb = wv * 16 + (ln >> 2);
        const int d8 = ln & 3;
        #pragma unroll
        for (int i = 0; i < 2; i++) {
            const int tt = tb + i * 64;
            const int l = (wh * 4 + (tt >> 5)) * 512 + ww * 32 + (tt & 31);
            const size_t g = (size_t)l * 768 + h * 32 + d8 * 8;
            async16(Qkv + g, &sQ[(wv * 16 + i * 64) * 32]);
            async16(Qkv + g + 256, &sK[(wv * 16 + i * 64) * 32]);
        }
        const u16* bsrc = Bg + (size_t)(n * 8 + h) * 16384;
        #pragma unroll
        for (int rr = 0; rr < 8; rr++)
            async16(bsrc + rr * 2048 + wv * 512 + ln * 8, &sPB[rr * 2048 + wv * 512]);
        #pragma unroll
        for (int i = 0; i < 2; i++) {
            const int tt = tb + i * 64;
            const int l = (wh * 4 + (tt >> 5)) * 512 + ww * 32 + (tt & 31);
            const uint4 raw = *(const uint4*)(Qkv + (size_t)l * 768 + 512 + h * 32 + d8 * 8);
            const u16* e = (const u16*)&raw;
            #pragma unroll
            for (int j = 0; j < 8; j++) sVt[(d8 * 8 + j) * 128 + tt] = e[j];
        }
    }
    __syncthreads();

    // S = Q K^T + bias. acc[i][j]: row t=wv*32+i*16+quad*4+r, col u=j*16+l16
    const f32x4 z4 = {0.f, 0.f, 0.f, 0.f};
    f32x4 acc[2][8];
    {
        bf16x8 qf[2], kf[8];
        #pragma unroll
        for (int i = 0; i < 2; i++) qf[i] = *(const bf16x8*)&sQ[(wv * 32 + i * 16 + l16) * 32 + quad * 8];
        #pragma unroll
        for (int j = 0; j < 8; j++) kf[j] = *(const bf16x8*)&sK[(j * 16 + l16) * 32 + quad * 8];
        #pragma unroll
        for (int i = 0; i < 2; i++)
            #pragma unroll
            for (int j = 0; j < 8; j++)
                acc[i][j] = __builtin_amdgcn_mfma_f32_16x16x32_bf16(qf[i], kf[j], z4, 0, 0, 0);
    }
    #pragma unroll
    for (int i = 0; i < 2; i++)
        #pragma unroll
        for (int j = 0; j < 8; j++)
            #pragma unroll
            for (int r = 0; r < 4; r++) {
                const int t = wv * 32 + i * 16 + quad * 4 + r;
                const unsigned bu = sPB[t * 128 + j * 16 + l16];
                acc[i][j][r] += __uint_as_float(bu << 16);
            }
    // softmax over u
    float rinv[2][4];
    #pragma unroll
    for (int i = 0; i < 2; i++) {
        #pragma unroll
        for (int r = 0; r < 4; r++) {
            float mx = acc[i][0][r];
            #pragma unroll
            for (int j = 1; j < 8; j++) mx = fmaxf(mx, acc[i][j][r]);
            #pragma unroll
            for (int m = 1; m < 16; m <<= 1) mx = fmaxf(mx, __shfl_xor(mx, m, 64));
            float sm = 0.f;
            #pragma unroll
            for (int j = 0; j < 8; j++) {
                const float p = __expf(acc[i][j][r] - mx);
                acc[i][j][r] = p;
                sm += p;
            }
            #pragma unroll
            for (int m = 1; m < 16; m <<= 1) sm += __shfl_xor(sm, m, 64);
            rinv[i][r] = 1.f / sm;
        }
    }
    __syncthreads();  // all waves done reading bias region before P overwrites it
    #pragma unroll
    for (int i = 0; i < 2; i++)
        #pragma unroll
        for (int j = 0; j < 8; j++)
            #pragma unroll
            for (int r = 0; r < 4; r++) {
                const int t = wv * 32 + i * 16 + quad * 4 + r;
                sPB[t * SPS + j * 16 + l16] = (u16)(__float_as_uint(acc[i][j][r]) >> 16);
            }
    __syncthreads();
    // O = P V
    f32x4 oacc[2][2];
    #pragma unroll
    for (int i = 0; i < 2; i++)
        #pragma unroll
        for (int jd = 0; jd < 2; jd++) oacc[i][jd] = z4;
    #pragma unroll
    for (int ku = 0; ku < 4; ku++) {
        bf16x8 pf[2], vf[2];
        #pragma unroll
        for (int i = 0; i < 2; i++) pf[i] = *(const bf16x8*)&sPB[(wv * 32 + i * 16 + l16) * SPS + ku * 32 + quad * 8];
        #pragma unroll
        for (int jd = 0; jd < 2; jd++) vf[jd] = *(const bf16x8*)&sVt[(jd * 16 + l16) * 128 + ku * 32 + quad * 8];
        #pragma unroll
        for (int i = 0; i < 2; i++)
            #pragma unroll
            for (int jd = 0; jd < 2; jd++)
                oacc[i][jd] = __builtin_amdgcn_mfma_f32_16x16x32_bf16(pf[i], vf[jd], oacc[i][jd], 0, 0, 0);
    }
    #pragma unroll
    for (int i = 0; i < 2; i++)
        #pragma unroll
        for (int jd = 0; jd < 2; jd++)
            #pragma unroll
            for (int r = 0; r < 4; r++) {
                const int t = wv * 32 + i * 16 + quad * 4 + r;
                const int d = jd * 16 + l16;
                const int l = (wh * 4 + (t >> 5)) * 512 + ww * 32 + (t & 31);
                Ob[(size_t)l * 256 + h * 32 + d] = f2bf(oacc[i][jd][r] * rinv[i][r]);
            }
}

extern "C" void kernel_launch(void* const* d_in, const int* in_sizes, int n_in,
                              void* d_out, int out_size, void* d_ws, size_t ws_size,
                              hipStream_t stream) {
    const float* x    = (const float*)d_in[0];
    const float* pos  = (const float*)d_in[1];
    const float* n1g  = (const float*)d_in[2];
    const float* n1b  = (const float*)d_in[3];
    const float* wq   = (const float*)d_in[4];
    const float* bq   = (const float*)d_in[5];
    const float* wk   = (const float*)d_in[6];
    const float* bk   = (const float*)d_in[7];
    const float* wvw  = (const float*)d_in[8];
    const float* bv   = (const float*)d_in[9];
    const float* wo   = (const float*)d_in[10];
    const float* bo   = (const float*)d_in[11];
    const float* n2g  = (const float*)d_in[12];
    const float* n2b  = (const float*)d_in[13];
    const float* wfc1 = (const float*)d_in[14];
    const float* bfc1 = (const float*)d_in[15];
    const float* wfc2 = (const float*)d_in[16];
    const float* bfc2 = (const float*)d_in[17];
    const float* pw1  = (const float*)d_in[18];
    const float* pb1  = (const float*)d_in[19];
    const float* bng  = (const float*)d_in[20];
    const float* bnb  = (const float*)d_in[21];
    const float* bnm  = (const float*)d_in[22];
    const float* bnv  = (const float*)d_in[23];
    const float* pw2  = (const float*)d_in[24];
    float* out = (float*)d_out;
    u16* ws  = (u16*)d_ws;

    const size_t SZ = (size_t)32768 * 256;  // one [L,C] bf16 slot
    u16* s0   = ws;                // xn -> O -> xn2
    u16* qkv  = ws + SZ;           // packed [L][768] QKV; later H (16384x1024) chunk
    u16* wqT  = ws + 4 * SZ;       // q,k,v transposed weights are CONTIGUOUS -> fused Wt
    u16* wkT  = wqT + 65536;
    u16* wvT  = wkT + 65536;
    u16* woT  = wvT + 65536;
    u16* fc1T = woT + 65536;
    u16* fc2T = fc1T + 262144;
    u16* biasg = fc2T + 262144;    // 256*8*128*128 bf16 = 67 MB

    transpose_all<<<768, dim3(32, 8), 0, stream>>>(wq, wk, wvw, wo, wfc1, wfc2,
                                                   wqT, wkT, wvT, woT, fc1T, fc2T);
    ln_k<<<8192, 256, 0, stream>>>(x, n1g, n1b, s0);
    // fused QKV projection: [32768,256] x [768,256]^T -> packed [32768,768]
    gemm_bt<<<dim3(6, 256), 256, 0, stream>>>(s0, wqT, bq, bk, bv, nullptr, qkv, nullptr,
                                              32768, 768, 256, 4);
    bias_k<<<256, 256, 0, stream>>>(pos, pw1, pb1, bng, bnb, bnm, bnv, pw2, biasg);
    attn_k<<<dim3(256, 8), 256, 0, stream>>>(qkv, biasg, s0);
    // X1 = x + O@wo + bo -> d_out (fp32)
    gemm_bt<<<dim3(2, 256), 256, 0, stream>>>(s0, woT, bo, nullptr, nullptr, x, nullptr, out,
                                              32768, 256, 256, 2);
    ln_k<<<8192, 256, 0, stream>>>(out, n2g, n2b, s0);
    // MLP in 2 row-chunks; H lives in the qkv slot region
    for (int c = 0; c < 2; c++) {
        const size_t ro = (size_t)c * 16384;
        gemm_bt<<<dim3(8, 128), 256, 0, stream>>>(s0 + ro * 256, fc1T, bfc1, nullptr, nullptr,
                                                  nullptr, qkv, nullptr, 16384, 1024, 256, 3);
        gemm_bt<<<dim3(2, 128), 256, 0, stream>>>(qkv, fc2T, bfc2, nullptr, nullptr,
                                                  out + ro * 256, nullptr, out + ro * 256,
                                                  16384, 256, 1024, 2);
    }
}

// Round 4
// 396.111 us; speedup vs baseline: 1.1095x; 1.0973x over previous
//
#include <hip/hip_runtime.h>
#include <cstdint>

typedef unsigned short u16;
typedef __bf16 bf16x8 __attribute__((ext_vector_type(8)));
typedef float f32x4 __attribute__((ext_vector_type(4)));

#define LN_EPS 1e-5f
#define SCALE_Q 0.17677669529663689f  // 32^-0.5

__device__ __forceinline__ u16 f2bf(float f) {
    union { float f; unsigned int i; } c; c.f = f;
    unsigned int r = c.i + 0x7FFFu + ((c.i >> 16) & 1u);
    return (u16)(r >> 16);
}
// pack two f32 -> two bf16 (truncation) in one v_perm_b32
__device__ __forceinline__ unsigned pack2(float hi, float lo) {
    return __builtin_amdgcn_perm(__float_as_uint(hi), __float_as_uint(lo), 0x07060302u);
}
// async global->LDS, 16B per lane; lds pointer must be wave-uniform
__device__ __forceinline__ void async16(const void* g, void* l) {
    __builtin_amdgcn_global_load_lds(
        (__attribute__((address_space(1))) unsigned int*)(unsigned long long)g,
        (__attribute__((address_space(3))) unsigned int*)l, 16, 0, 0);
}

// ------------- all 6 weight transposes (+bf16 cast) in one dispatch -------------
__global__ void transpose_all(const float* __restrict__ wq, const float* __restrict__ wk,
                              const float* __restrict__ wv, const float* __restrict__ wo,
                              const float* __restrict__ f1, const float* __restrict__ f2,
                              u16* oq, u16* ok, u16* ov, u16* oo, u16* o1, u16* o2) {
    __shared__ float tile[32][33];
    const int b = blockIdx.x;
    const float* In; u16* Out; int R, C, bx, by;
    if (b < 256) {
        const int m = b >> 6, l = b & 63;
        In = m == 0 ? wq : (m == 1 ? wk : (m == 2 ? wv : wo));
        Out = m == 0 ? oq : (m == 1 ? ok : (m == 2 ? ov : oo));
        R = 256; C = 256; bx = (l & 7) * 32; by = (l >> 3) * 32;
    } else if (b < 512) {
        const int l = b - 256; In = f1; Out = o1; R = 256; C = 1024;
        bx = (l & 31) * 32; by = (l >> 5) * 32;
    } else {
        const int l = b - 512; In = f2; Out = o2; R = 1024; C = 256;
        bx = (l & 7) * 32; by = (l >> 3) * 32;
    }
    const int tx = threadIdx.x, ty = threadIdx.y;
    for (int i = 0; i < 32; i += 8)
        tile[ty + i][tx] = In[(size_t)(by + ty + i) * C + bx + tx];
    __syncthreads();
    for (int i = 0; i < 32; i += 8)
        Out[(size_t)(bx + ty + i) * R + by + tx] = f2bf(tile[tx][ty + i]);
}

// ------------- LayerNorm: one wave per token (C=256); fp32 in -> bf16 out -------------
__global__ __launch_bounds__(256) void ln_k(const float* __restrict__ X, const float* __restrict__ G,
                                            const float* __restrict__ Bt, u16* __restrict__ Y) {
    const int token = blockIdx.x * 4 + (threadIdx.x >> 6);
    const int ln = threadIdx.x & 63;
    const float4 rv = *(const float4*)(X + (size_t)token * 256 + ln * 4);
    float s = rv.x + rv.y + rv.z + rv.w;
    float q = rv.x * rv.x + rv.y * rv.y + rv.z * rv.z + rv.w * rv.w;
    #pragma unroll
    for (int m = 1; m < 64; m <<= 1) { s += __shfl_xor(s, m, 64); q += __shfl_xor(q, m, 64); }
    const float mean = s * (1.f / 256.f);
    const float var  = q * (1.f / 256.f) - mean * mean;
    const float rs   = rsqrtf(var + LN_EPS);
    const float4 gv = *(const float4*)(G + ln * 4);
    const float4 bv = *(const float4*)(Bt + ln * 4);
    ushort4 o;
    o.x = f2bf((rv.x - mean) * rs * gv.x + bv.x);
    o.y = f2bf((rv.y - mean) * rs * gv.y + bv.y);
    o.z = f2bf((rv.z - mean) * rs * gv.z + bv.z);
    o.w = f2bf((rv.w - mean) * rs * gv.w + bv.w);
    *(ushort4*)(Y + (size_t)token * 256 + ln * 4) = o;
}

// ------------- GEMM (B^T form): Y[m,n] = sum_k X[m,k]*Wt[n,k] + epilogue -------------
// mode: 2 = +bias + Res[m,n] (fp32 out) ; 4 = fused-QKV (seg bias, Q scaled, bf16 out)
// bf16 outputs are staged through LDS for coalesced 16B stores.
__global__ __launch_bounds__(256, 2) void gemm_bt(
    const u16* __restrict__ X, const u16* __restrict__ Wt,
    const float* __restrict__ B1, const float* __restrict__ B2, const float* __restrict__ B3,
    const float* __restrict__ Res,
    u16* __restrict__ Ybf, float* __restrict__ Yf,
    int M, int N, int K, int mode) {
    __shared__ alignas(16) u16 sBuf[128 * 128];  // K-loop: sA=sBuf, sB=sBuf+8192; epilogue: C tile
    u16* sA = sBuf;
    u16* sB = sBuf + 128 * 64;
    const int tid = threadIdx.x, wv = tid >> 6, ln = tid & 63;
    const int quad = ln >> 4, l16 = ln & 15;
    const int m0 = blockIdx.y * 128, n0 = blockIdx.x * 128;
    const int mw = (wv >> 1) * 64, nw = (wv & 1) * 64;
    const int r8 = ln >> 3, c8 = ln & 7;
    const f32x4 z4 = {0.f, 0.f, 0.f, 0.f};
    f32x4 acc[4][4];
    #pragma unroll
    for (int i = 0; i < 4; i++)
        #pragma unroll
        for (int j = 0; j < 4; j++) acc[i][j] = z4;

    for (int k0 = 0; k0 < K; k0 += 64) {
        __syncthreads();
        #pragma unroll
        for (int i = 0; i < 4; i++) {
            const int row = wv * 32 + i * 8;
            async16(X  + (size_t)(m0 + row + r8) * K + k0 + c8 * 8, &sA[row * 64]);
            async16(Wt + (size_t)(n0 + row + r8) * K + k0 + c8 * 8, &sB[row * 64]);
        }
        __syncthreads();
        #pragma unroll
        for (int kk = 0; kk < 2; kk++) {
            bf16x8 af[4], bfr[4];
            #pragma unroll
            for (int i = 0; i < 4; i++) af[i]  = *(const bf16x8*)&sA[(mw + i * 16 + l16) * 64 + kk * 32 + quad * 8];
            #pragma unroll
            for (int j = 0; j < 4; j++) bfr[j] = *(const bf16x8*)&sB[(nw + j * 16 + l16) * 64 + kk * 32 + quad * 8];
            #pragma unroll
            for (int i = 0; i < 4; i++)
                #pragma unroll
                for (int j = 0; j < 4; j++)
                    acc[i][j] = __builtin_amdgcn_mfma_f32_16x16x32_bf16(af[i], bfr[j], acc[i][j], 0, 0, 0);
        }
    }
    // epilogue
    const int seg = n0 >> 8;  // for mode 4 (block fully inside one 256-col segment)
    const float* bp = (mode == 4) ? (seg == 0 ? B1 : (seg == 1 ? B2 : B3)) : B1;
    const float sc = (mode == 4 && seg == 0) ? SCALE_Q : 1.f;
    if (mode == 4) {
        __syncthreads();  // done with sA/sB staging reads
        #pragma unroll
        for (int j = 0; j < 4; j++) {
            const int col = nw + j * 16 + l16;
            const float bc = bp[(n0 + col) & 255];
            #pragma unroll
            for (int i = 0; i < 4; i++)
                #pragma unroll
                for (int r = 0; r < 4; r++)
                    sBuf[(mw + i * 16 + quad * 4 + r) * 128 + col] = f2bf((acc[i][j][r] + bc) * sc);
        }
        __syncthreads();
        // coalesced stores: 128 rows x 256B
        #pragma unroll
        for (int it = 0; it < 8; it++) {
            const int idx = it * 256 + tid;
            const int row = idx >> 4, sg = idx & 15;
            *(uint4*)(Ybf + (size_t)(m0 + row) * N + n0 + sg * 8) = *(const uint4*)&sBuf[row * 128 + sg * 8];
        }
    } else {
        #pragma unroll
        for (int j = 0; j < 4; j++) {
            const int col = n0 + nw + j * 16 + l16;
            const float bc = bp[col];
            #pragma unroll
            for (int i = 0; i < 4; i++) {
                #pragma unroll
                for (int r = 0; r < 4; r++) {
                    const int row = m0 + mw + i * 16 + quad * 4 + r;
                    float v = acc[i][j][r] + bc;
                    if (mode == 2) v += Res[(size_t)row * N + col];
                    Yf[(size_t)row * N + col] = v;
                }
            }
        }
    }
}

// ------------- per-window bias: bias[h][t][u] = sum_o pw2[h][o]*relu(ta2[o][t]-ta[o][u]) -------------
__global__ __launch_bounds__(256) void bias_k(
    const float* __restrict__ pos, const float* __restrict__ pw1, const float* __restrict__ pb1,
    const float* __restrict__ bng, const float* __restrict__ bnb, const float* __restrict__ bnm,
    const float* __restrict__ bnv, const float* __restrict__ pw2, u16* __restrict__ Bg) {
    __shared__ float sTa[32 * 128], sTa2[32 * 128];  // o padded 16->32 with zeros
    __shared__ u16 sW[16 * 32];
    __shared__ alignas(16) u16 sOut[4][8 * 128];     // per-wave [h][u] staging for one t
    const int n = blockIdx.x, wh = n >> 4, ww = n & 15;
    const int tid = threadIdx.x, wv = tid >> 6, ln = tid & 63;
    const int quad = ln >> 4, l16 = ln & 15;
    for (int r = 0; r < 16; r++) {
        const int e = tid + r * 256, o = e >> 7, t = e & 127;
        float ta = 0.f, ta2 = 0.f;
        if (o < 16) {
            const int l = (wh * 4 + (t >> 5)) * 512 + ww * 32 + (t & 31);
            const float sv = rsqrtf(bnv[o] + LN_EPS) * bng[o];
            ta = sv * (pw1[o * 2] * pos[l * 2] + pw1[o * 2 + 1] * pos[l * 2 + 1]);
            ta2 = ta + (pb1[o] - bnm[o]) * sv + bnb[o];
        }
        sTa[o * 128 + t] = ta; sTa2[o * 128 + t] = ta2;
    }
    for (int r = 0; r < 2; r++) {
        const int e = tid + r * 256, h = e >> 5, o = e & 31;
        sW[e] = (h < 8 && o < 16) ? f2bf(pw2[h * 16 + o]) : (u16)0;
    }
    __syncthreads();
    const bf16x8 af = *(const bf16x8*)&sW[l16 * 32 + quad * 8];
    float uo[8][8];
    #pragma unroll
    for (int c = 0; c < 8; c++)
        #pragma unroll
        for (int j = 0; j < 8; j++)
            uo[c][j] = sTa[(quad * 8 + j) * 128 + c * 16 + l16];
    const f32x4 z4 = {0.f, 0.f, 0.f, 0.f};
    u16* outb = Bg + (size_t)n * 131072;  // 8*128*128
    for (int tl = 0; tl < 32; tl++) {
        const int t = wv * 32 + tl;
        float t2[8];
        #pragma unroll
        for (int j = 0; j < 8; j++) t2[j] = sTa2[(quad * 8 + j) * 128 + t];
        #pragma unroll
        for (int c = 0; c < 8; c++) {
            float rl[8];
            #pragma unroll
            for (int j = 0; j < 8; j++) rl[j] = fmaxf(t2[j] - uo[c][j], 0.f);
            union { unsigned u[4]; bf16x8 v; } bb;
            #pragma unroll
            for (int p = 0; p < 4; p++) bb.u[p] = pack2(rl[2 * p + 1], rl[2 * p]);
            const f32x4 cc = __builtin_amdgcn_mfma_f32_16x16x32_bf16(af, bb.v, z4, 0, 0, 0);
            if (quad < 2) {
                #pragma unroll
                for (int r = 0; r < 4; r++)
                    sOut[wv][(quad * 4 + r) * 128 + c * 16 + l16] =
                        (u16)(__float_as_uint(cc[r]) >> 16);
            }
        }
        // coalesced flush: 8 h-rows x 256B (wave-local, ds ordering within wave)
        #pragma unroll
        for (int it = 0; it < 2; it++) {
            const int idx = it * 64 + ln;
            const int h = idx >> 4, u8 = idx & 15;
            *(uint4*)(outb + (size_t)h * 16384 + t * 128 + u8 * 8) = *(const uint4*)&sOut[wv][idx * 8];
        }
    }
}

// ------------- windowed attention, one block per (window, head) -------------
__global__ __launch_bounds__(256, 2) void attn_k(
    const u16* __restrict__ Qkv, const u16* __restrict__ Bg, u16* __restrict__ Ob) {
    constexpr int SPS = 136;
    __shared__ alignas(16) u16 sQ[128 * 32];
    __shared__ alignas(16) u16 sK[128 * 32];
    __shared__ alignas(16) u16 sVt[32 * 128];
    __shared__ alignas(16) u16 sPB[128 * SPS];  // bias tile (stride 128), then P (stride 136)

    const int n = blockIdx.x, h = blockIdx.y;
    const int tid = threadIdx.x, wv = tid >> 6, ln = tid & 63;
    const int quad = ln >> 4, l16 = ln & 15;
    const int wh = n >> 4, ww = n & 15;

    {
        const int tb = wv * 16 + (ln >> 2);
        const int d8 = ln & 3;
        #pragma unroll
        for (int i = 0; i < 2; i++) {
            const int tt = tb + i * 64;
            const int l = (wh * 4 + (tt >> 5)) * 512 + ww * 32 + (tt & 31);
            const size_t g = (size_t)l * 768 + h * 32 + d8 * 8;
            async16(Qkv + g, &sQ[(wv * 16 + i * 64) * 32]);
            async16(Qkv + g + 256, &sK[(wv * 16 + i * 64) * 32]);
        }
        const u16* bsrc = Bg + (size_t)(n * 8 + h) * 16384;
        #pragma unroll
        for (int rr = 0; rr < 8; rr++)
            async16(bsrc + rr * 2048 + wv * 512 + ln * 8, &sPB[rr * 2048 + wv * 512]);
        #pragma unroll
        for (int i = 0; i < 2; i++) {
            const int tt = tb + i * 64;
            const int l = (wh * 4 + (tt >> 5)) * 512 + ww * 32 + (tt & 31);
            const uint4 raw = *(const uint4*)(Qkv + (size_t)l * 768 + 512 + h * 32 + d8 * 8);
            const u16* e = (const u16*)&raw;
            #pragma unroll
            for (int j = 0; j < 8; j++) sVt[(d8 * 8 + j) * 128 + tt] = e[j];
        }
    }
    __syncthreads();

    const f32x4 z4 = {0.f, 0.f, 0.f, 0.f};
    f32x4 acc[2][8];
    {
        bf16x8 qf[2], kf[8];
        #pragma unroll
        for (int i = 0; i < 2; i++) qf[i] = *(const bf16x8*)&sQ[(wv * 32 + i * 16 + l16) * 32 + quad * 8];
        #pragma unroll
        for (int j = 0; j < 8; j++) kf[j] = *(const bf16x8*)&sK[(j * 16 + l16) * 32 + quad * 8];
        #pragma unroll
        for (int i = 0; i < 2; i++)
            #pragma unroll
            for (int j = 0; j < 8; j++)
                acc[i][j] = __builtin_amdgcn_mfma_f32_16x16x32_bf16(qf[i], kf[j], z4, 0, 0, 0);
    }
    #pragma unroll
    for (int i = 0; i < 2; i++)
        #pragma unroll
        for (int j = 0; j < 8; j++)
            #pragma unroll
            for (int r = 0; r < 4; r++) {
                const int t = wv * 32 + i * 16 + quad * 4 + r;
                const unsigned bu = sPB[t * 128 + j * 16 + l16];
                acc[i][j][r] += __uint_as_float(bu << 16);
            }
    float rinv[2][4];
    #pragma unroll
    for (int i = 0; i < 2; i++) {
        #pragma unroll
        for (int r = 0; r < 4; r++) {
            float mx = acc[i][0][r];
            #pragma unroll
            for (int j = 1; j < 8; j++) mx = fmaxf(mx, acc[i][j][r]);
            #pragma unroll
            for (int m = 1; m < 16; m <<= 1) mx = fmaxf(mx, __shfl_xor(mx, m, 64));
            float sm = 0.f;
            #pragma unroll
            for (int j = 0; j < 8; j++) {
                const float p = __expf(acc[i][j][r] - mx);
                acc[i][j][r] = p;
                sm += p;
            }
            #pragma unroll
            for (int m = 1; m < 16; m <<= 1) sm += __shfl_xor(sm, m, 64);
            rinv[i][r] = 1.f / sm;
        }
    }
    __syncthreads();
    #pragma unroll
    for (int i = 0; i < 2; i++)
        #pragma unroll
        for (int j = 0; j < 8; j++)
            #pragma unroll
            for (int r = 0; r < 4; r++) {
                const int t = wv * 32 + i * 16 + quad * 4 + r;
                sPB[t * SPS + j * 16 + l16] = (u16)(__float_as_uint(acc[i][j][r]) >> 16);
            }
    __syncthreads();
    f32x4 oacc[2][2];
    #pragma unroll
    for (int i = 0; i < 2; i++)
        #pragma unroll
        for (int jd = 0; jd < 2; jd++) oacc[i][jd] = z4;
    #pragma unroll
    for (int ku = 0; ku < 4; ku++) {
        bf16x8 pf[2], vf[2];
        #pragma unroll
        for (int i = 0; i < 2; i++) pf[i] = *(const bf16x8*)&sPB[(wv * 32 + i * 16 + l16) * SPS + ku * 32 + quad * 8];
        #pragma unroll
        for (int jd = 0; jd < 2; jd++) vf[jd] = *(const bf16x8*)&sVt[(jd * 16 + l16) * 128 + ku * 32 + quad * 8];
        #pragma unroll
        for (int i = 0; i < 2; i++)
            #pragma unroll
            for (int jd = 0; jd < 2; jd++)
                oacc[i][jd] = __builtin_amdgcn_mfma_f32_16x16x32_bf16(pf[i], vf[jd], oacc[i][jd], 0, 0, 0);
    }
    #pragma unroll
    for (int i = 0; i < 2; i++)
        #pragma unroll
        for (int jd = 0; jd < 2; jd++)
            #pragma unroll
            for (int r = 0; r < 4; r++) {
                const int t = wv * 32 + i * 16 + quad * 4 + r;
                const int d = jd * 16 + l16;
                const int l = (wh * 4 + (t >> 5)) * 512 + ww * 32 + (t & 31);
                Ob[(size_t)l * 256 + h * 32 + d] = f2bf(oacc[i][jd][r] * rinv[i][r]);
            }
}

// ------------- fused MLP: out[m] += gelu(xn2[m]@fc1 + b1)@fc2 + b2  (H never hits HBM) -------------
// One block per 64-row tile. sA = xn2 tile [64x256] staged once; per 128-col H-chunk:
// fc1 tile -> gelu -> sH [64x128] bf16 -> accumulate into persistent 64x256 fp32 fc2 acc.
// B-fragments for both weights read directly from global (L2-resident, 0.5MB each).
__global__ __launch_bounds__(256, 2) void mlp_fused(
    const u16* __restrict__ Xn, const u16* __restrict__ fc1T, const u16* __restrict__ fc2T,
    const float* __restrict__ b1, const float* __restrict__ b2, float* __restrict__ Out) {
    __shared__ alignas(16) u16 sA[64 * 256];  // 32KB
    __shared__ alignas(16) u16 sH[64 * 128];  // 16KB
    const int tid = threadIdx.x, wv = tid >> 6, ln = tid & 63;
    const int quad = ln >> 4, l16 = ln & 15;
    const int m0 = blockIdx.x * 64;
    const int mw = (wv >> 1) * 32;         // 2-way M split
    const int nw1 = (wv & 1) * 64;         // fc1 N split (128 cols)
    const int nw2 = (wv & 1) * 128;        // fc2 N split (256 cols)

    // stage A once: 64x256 bf16, 8 async16 rounds
    #pragma unroll
    for (int rr = 0; rr < 8; rr++) {
        const int row = rr * 8 + wv * 2 + (ln >> 5);
        async16(Xn + (size_t)(m0 + row) * 256 + (ln & 31) * 8, &sA[(rr * 8 + wv * 2) * 256]);
    }

    const f32x4 z4 = {0.f, 0.f, 0.f, 0.f};
    f32x4 acc2[2][8];
    #pragma unroll
    for (int i = 0; i < 2; i++)
        #pragma unroll
        for (int j = 0; j < 8; j++) acc2[i][j] = z4;

    __syncthreads();
    for (int c = 0; c < 8; c++) {
        // fc1: C1[64x128] for cols c*128..+127, K=256
        f32x4 acc1[2][4];
        #pragma unroll
        for (int i = 0; i < 2; i++)
            #pragma unroll
            for (int j = 0; j < 4; j++) acc1[i][j] = z4;
        for (int kc = 0; kc < 8; kc++) {
            bf16x8 af[2], bfr[4];
            #pragma unroll
            for (int i = 0; i < 2; i++)
                af[i] = *(const bf16x8*)&sA[(mw + i * 16 + l16) * 256 + kc * 32 + quad * 8];
            #pragma unroll
            for (int j = 0; j < 4; j++)
                bfr[j] = *(const bf16x8*)(fc1T + (size_t)(c * 128 + nw1 + j * 16 + l16) * 256 + kc * 32 + quad * 8);
            #pragma unroll
            for (int i = 0; i < 2; i++)
                #pragma unroll
                for (int j = 0; j < 4; j++)
                    acc1[i][j] = __builtin_amdgcn_mfma_f32_16x16x32_bf16(af[i], bfr[j], acc1[i][j], 0, 0, 0);
        }
        __syncthreads();  // previous c's fc2 reads of sH complete
        #pragma unroll
        for (int j = 0; j < 4; j++) {
            const float bc = b1[c * 128 + nw1 + j * 16 + l16];
            #pragma unroll
            for (int i = 0; i < 2; i++)
                #pragma unroll
                for (int r = 0; r < 4; r++) {
                    float v = acc1[i][j][r] + bc;
                    const float p = v * v;
                    const float qq = fmaf(p, -0.07135481283f, -1.5957691216f);
                    v = v / (1.f + __expf(v * qq));  // gelu approx
                    sH[(mw + i * 16 + quad * 4 + r) * 128 + nw1 + j * 16 + l16] = f2bf(v);
                }
        }
        __syncthreads();
        // fc2 accumulate: K-chunk = cols c*128..+127 of H
        for (int kc = 0; kc < 4; kc++) {
            bf16x8 pf[2], bfr[8];
            #pragma unroll
            for (int i = 0; i < 2; i++)
                pf[i] = *(const bf16x8*)&sH[(mw + i * 16 + l16) * 128 + kc * 32 + quad * 8];
            #pragma unroll
            for (int j = 0; j < 8; j++)
                bfr[j] = *(const bf16x8*)(fc2T + (size_t)(nw2 + j * 16 + l16) * 1024 + c * 128 + kc * 32 + quad * 8);
            #pragma unroll
            for (int i = 0; i < 2; i++)
                #pragma unroll
                for (int j = 0; j < 8; j++)
                    acc2[i][j] = __builtin_amdgcn_mfma_f32_16x16x32_bf16(pf[i], bfr[j], acc2[i][j], 0, 0, 0);
        }
    }
    // epilogue: out = acc2 + b2 + out (residual, in-place; fp32 coalesced 64B per quad)
    #pragma unroll
    for (int j = 0; j < 8; j++) {
        const int col = nw2 + j * 16 + l16;
        const float bc = b2[col];
        #pragma unroll
        for (int i = 0; i < 2; i++)
            #pragma unroll
            for (int r = 0; r < 4; r++) {
                const size_t idx = (size_t)(m0 + mw + i * 16 + quad * 4 + r) * 256 + col;
                Out[idx] = acc2[i][j][r] + bc + Out[idx];
            }
    }
}

extern "C" void kernel_launch(void* const* d_in, const int* in_sizes, int n_in,
                              void* d_out, int out_size, void* d_ws, size_t ws_size,
                              hipStream_t stream) {
    const float* x    = (const float*)d_in[0];
    const float* pos  = (const float*)d_in[1];
    const float* n1g  = (const float*)d_in[2];
    const float* n1b  = (const float*)d_in[3];
    const float* wq   = (const float*)d_in[4];
    const float* bq   = (const float*)d_in[5];
    const float* wk   = (const float*)d_in[6];
    const float* bk   = (const float*)d_in[7];
    const float* wvw  = (const float*)d_in[8];
    const float* bv   = (const float*)d_in[9];
    const float* wo   = (const float*)d_in[10];
    const float* bo   = (const float*)d_in[11];
    const float* n2g  = (const float*)d_in[12];
    const float* n2b  = (const float*)d_in[13];
    const float* wfc1 = (const float*)d_in[14];
    const float* bfc1 = (const float*)d_in[15];
    const float* wfc2 = (const float*)d_in[16];
    const float* bfc2 = (const float*)d_in[17];
    const float* pw1  = (const float*)d_in[18];
    const float* pb1  = (const float*)d_in[19];
    const float* bng  = (const float*)d_in[20];
    const float* bnb  = (const float*)d_in[21];
    const float* bnm  = (const float*)d_in[22];
    const float* bnv  = (const float*)d_in[23];
    const float* pw2  = (const float*)d_in[24];
    float* out = (float*)d_out;
    u16* ws  = (u16*)d_ws;

    const size_t SZ = (size_t)32768 * 256;  // one [L,C] bf16 slot
    u16* s0   = ws;                // xn -> O -> xn2
    u16* qkv  = ws + SZ;           // packed [L][768] QKV (3 slots)
    u16* wqT  = ws + 4 * SZ;       // q,k,v transposed weights CONTIGUOUS -> fused Wt
    u16* wkT  = wqT + 65536;
    u16* wvT  = wkT + 65536;
    u16* woT  = wvT + 65536;
    u16* fc1T = woT + 65536;
    u16* fc2T = fc1T + 262144;
    u16* biasg = fc2T + 262144;    // 256*8*128*128 bf16 = 67 MB

    transpose_all<<<768, dim3(32, 8), 0, stream>>>(wq, wk, wvw, wo, wfc1, wfc2,
                                                   wqT, wkT, wvT, woT, fc1T, fc2T);
    ln_k<<<8192, 256, 0, stream>>>(x, n1g, n1b, s0);
    // fused QKV projection: [32768,256] x [768,256]^T -> packed [32768,768]
    gemm_bt<<<dim3(6, 256), 256, 0, stream>>>(s0, wqT, bq, bk, bv, nullptr, qkv, nullptr,
                                              32768, 768, 256, 4);
    bias_k<<<256, 256, 0, stream>>>(pos, pw1, pb1, bng, bnb, bnm, bnv, pw2, biasg);
    attn_k<<<dim3(256, 8), 256, 0, stream>>>(qkv, biasg, s0);
    // X1 = x + O@wo + bo -> d_out (fp32)
    gemm_bt<<<dim3(2, 256), 256, 0, stream>>>(s0, woT, bo, nullptr, nullptr, x, nullptr, out,
                                              32768, 256, 256, 2);
    ln_k<<<8192, 256, 0, stream>>>(out, n2g, n2b, s0);
    // fused MLP: out += gelu(xn2@fc1+b1)@fc2+b2, H stays on-chip
    mlp_fused<<<512, 256, 0, stream>>>(s0, fc1T, fc2T, bfc1, bfc2, out);
}

// Round 5
// 364.496 us; speedup vs baseline: 1.2057x; 1.0867x over previous
//
#include <hip/hip_runtime.h>
#include <cstdint>

typedef unsigned short u16;
typedef __bf16 bf16x8 __attribute__((ext_vector_type(8)));
typedef float f32x4 __attribute__((ext_vector_type(4)));

#define LN_EPS 1e-5f
#define SCALE_Q 0.17677669529663689f  // 32^-0.5

__device__ __forceinline__ u16 f2bf(float f) {
    union { float f; unsigned int i; } c; c.f = f;
    unsigned int r = c.i + 0x7FFFu + ((c.i >> 16) & 1u);
    return (u16)(r >> 16);
}
// pack two f32 -> two bf16 (truncation) in one v_perm_b32
__device__ __forceinline__ unsigned pack2(float hi, float lo) {
    return __builtin_amdgcn_perm(__float_as_uint(hi), __float_as_uint(lo), 0x07060302u);
}
// async global->LDS, 16B per lane; lds pointer must be wave-uniform
__device__ __forceinline__ void async16(const void* g, void* l) {
    __builtin_amdgcn_global_load_lds(
        (__attribute__((address_space(1))) unsigned int*)(unsigned long long)g,
        (__attribute__((address_space(3))) unsigned int*)l, 16, 0, 0);
}

// ------------- all 6 weight transposes (+bf16 cast) in one dispatch -------------
__global__ void transpose_all(const float* __restrict__ wq, const float* __restrict__ wk,
                              const float* __restrict__ wv, const float* __restrict__ wo,
                              const float* __restrict__ f1, const float* __restrict__ f2,
                              u16* oq, u16* ok, u16* ov, u16* oo, u16* o1, u16* o2) {
    __shared__ float tile[32][33];
    const int b = blockIdx.x;
    const float* In; u16* Out; int R, C, bx, by;
    if (b < 256) {
        const int m = b >> 6, l = b & 63;
        In = m == 0 ? wq : (m == 1 ? wk : (m == 2 ? wv : wo));
        Out = m == 0 ? oq : (m == 1 ? ok : (m == 2 ? ov : oo));
        R = 256; C = 256; bx = (l & 7) * 32; by = (l >> 3) * 32;
    } else if (b < 512) {
        const int l = b - 256; In = f1; Out = o1; R = 256; C = 1024;
        bx = (l & 31) * 32; by = (l >> 5) * 32;
    } else {
        const int l = b - 512; In = f2; Out = o2; R = 1024; C = 256;
        bx = (l & 7) * 32; by = (l >> 3) * 32;
    }
    const int tx = threadIdx.x, ty = threadIdx.y;
    for (int i = 0; i < 32; i += 8)
        tile[ty + i][tx] = In[(size_t)(by + ty + i) * C + bx + tx];
    __syncthreads();
    for (int i = 0; i < 32; i += 8)
        Out[(size_t)(bx + ty + i) * R + by + tx] = f2bf(tile[tx][ty + i]);
}

// ------------- LayerNorm: one wave per token (C=256); fp32 in -> bf16 out -------------
__global__ __launch_bounds__(256) void ln_k(const float* __restrict__ X, const float* __restrict__ G,
                                            const float* __restrict__ Bt, u16* __restrict__ Y) {
    const int token = blockIdx.x * 4 + (threadIdx.x >> 6);
    const int ln = threadIdx.x & 63;
    const float4 rv = *(const float4*)(X + (size_t)token * 256 + ln * 4);
    float s = rv.x + rv.y + rv.z + rv.w;
    float q = rv.x * rv.x + rv.y * rv.y + rv.z * rv.z + rv.w * rv.w;
    #pragma unroll
    for (int m = 1; m < 64; m <<= 1) { s += __shfl_xor(s, m, 64); q += __shfl_xor(q, m, 64); }
    const float mean = s * (1.f / 256.f);
    const float var  = q * (1.f / 256.f) - mean * mean;
    const float rs   = rsqrtf(var + LN_EPS);
    const float4 gv = *(const float4*)(G + ln * 4);
    const float4 bv = *(const float4*)(Bt + ln * 4);
    ushort4 o;
    o.x = f2bf((rv.x - mean) * rs * gv.x + bv.x);
    o.y = f2bf((rv.y - mean) * rs * gv.y + bv.y);
    o.z = f2bf((rv.z - mean) * rs * gv.z + bv.z);
    o.w = f2bf((rv.w - mean) * rs * gv.w + bv.w);
    *(ushort4*)(Y + (size_t)token * 256 + ln * 4) = o;
}

// ------------- GEMM (B^T form): Y[m,n] = sum_k X[m,k]*Wt[n,k] + epilogue -------------
// mode: 2 = +bias + Res[m,n] (fp32 out) ; 4 = fused-QKV (seg bias, Q scaled, bf16 out)
__global__ __launch_bounds__(256, 2) void gemm_bt(
    const u16* __restrict__ X, const u16* __restrict__ Wt,
    const float* __restrict__ B1, const float* __restrict__ B2, const float* __restrict__ B3,
    const float* __restrict__ Res,
    u16* __restrict__ Ybf, float* __restrict__ Yf,
    int M, int N, int K, int mode) {
    __shared__ alignas(16) u16 sBuf[128 * 128];  // K-loop: sA=sBuf, sB=sBuf+8192; epilogue: C tile
    u16* sA = sBuf;
    u16* sB = sBuf + 128 * 64;
    const int tid = threadIdx.x, wv = tid >> 6, ln = tid & 63;
    const int quad = ln >> 4, l16 = ln & 15;
    const int m0 = blockIdx.y * 128, n0 = blockIdx.x * 128;
    const int mw = (wv >> 1) * 64, nw = (wv & 1) * 64;
    const int r8 = ln >> 3, c8 = ln & 7;
    const f32x4 z4 = {0.f, 0.f, 0.f, 0.f};
    f32x4 acc[4][4];
    #pragma unroll
    for (int i = 0; i < 4; i++)
        #pragma unroll
        for (int j = 0; j < 4; j++) acc[i][j] = z4;

    for (int k0 = 0; k0 < K; k0 += 64) {
        __syncthreads();
        #pragma unroll
        for (int i = 0; i < 4; i++) {
            const int row = wv * 32 + i * 8;
            async16(X  + (size_t)(m0 + row + r8) * K + k0 + c8 * 8, &sA[row * 64]);
            async16(Wt + (size_t)(n0 + row + r8) * K + k0 + c8 * 8, &sB[row * 64]);
        }
        __syncthreads();
        #pragma unroll
        for (int kk = 0; kk < 2; kk++) {
            bf16x8 af[4], bfr[4];
            #pragma unroll
            for (int i = 0; i < 4; i++) af[i]  = *(const bf16x8*)&sA[(mw + i * 16 + l16) * 64 + kk * 32 + quad * 8];
            #pragma unroll
            for (int j = 0; j < 4; j++) bfr[j] = *(const bf16x8*)&sB[(nw + j * 16 + l16) * 64 + kk * 32 + quad * 8];
            #pragma unroll
            for (int i = 0; i < 4; i++)
                #pragma unroll
                for (int j = 0; j < 4; j++)
                    acc[i][j] = __builtin_amdgcn_mfma_f32_16x16x32_bf16(af[i], bfr[j], acc[i][j], 0, 0, 0);
        }
    }
    // epilogue
    const int seg = n0 >> 8;  // for mode 4 (block fully inside one 256-col segment)
    const float* bp = (mode == 4) ? (seg == 0 ? B1 : (seg == 1 ? B2 : B3)) : B1;
    const float sc = (mode == 4 && seg == 0) ? SCALE_Q : 1.f;
    if (mode == 4) {
        __syncthreads();  // done with sA/sB staging reads
        #pragma unroll
        for (int j = 0; j < 4; j++) {
            const int col = nw + j * 16 + l16;
            const float bc = bp[(n0 + col) & 255];
            #pragma unroll
            for (int i = 0; i < 4; i++)
                #pragma unroll
                for (int r = 0; r < 4; r++)
                    sBuf[(mw + i * 16 + quad * 4 + r) * 128 + col] = f2bf((acc[i][j][r] + bc) * sc);
        }
        __syncthreads();
        // coalesced stores: 128 rows x 256B
        #pragma unroll
        for (int it = 0; it < 8; it++) {
            const int idx = it * 256 + tid;
            const int row = idx >> 4, sg = idx & 15;
            *(uint4*)(Ybf + (size_t)(m0 + row) * N + n0 + sg * 8) = *(const uint4*)&sBuf[row * 128 + sg * 8];
        }
    } else {
        #pragma unroll
        for (int j = 0; j < 4; j++) {
            const int col = n0 + nw + j * 16 + l16;
            const float bc = bp[col];
            #pragma unroll
            for (int i = 0; i < 4; i++) {
                #pragma unroll
                for (int r = 0; r < 4; r++) {
                    const int row = m0 + mw + i * 16 + quad * 4 + r;
                    float v = acc[i][j][r] + bc;
                    if (mode == 2) v += Res[(size_t)row * N + col];
                    Yf[(size_t)row * N + col] = v;
                }
            }
        }
    }
}

// ------------- per-window bias: bias[h][t][u] = sum_o pw2[h][o]*relu(ta2[o][t]-ta[o][u]) -------------
__global__ __launch_bounds__(256) void bias_k(
    const float* __restrict__ pos, const float* __restrict__ pw1, const float* __restrict__ pb1,
    const float* __restrict__ bng, const float* __restrict__ bnb, const float* __restrict__ bnm,
    const float* __restrict__ bnv, const float* __restrict__ pw2, u16* __restrict__ Bg) {
    __shared__ float sTa[32 * 128], sTa2[32 * 128];  // o padded 16->32 with zeros
    __shared__ u16 sW[16 * 32];
    __shared__ alignas(16) u16 sOut[4][8 * 128];     // per-wave [h][u] staging for one t
    const int n = blockIdx.x, wh = n >> 4, ww = n & 15;
    const int tid = threadIdx.x, wv = tid >> 6, ln = tid & 63;
    const int quad = ln >> 4, l16 = ln & 15;
    for (int r = 0; r < 16; r++) {
        const int e = tid + r * 256, o = e >> 7, t = e & 127;
        float ta = 0.f, ta2 = 0.f;
        if (o < 16) {
            const int l = (wh * 4 + (t >> 5)) * 512 + ww * 32 + (t & 31);
            const float sv = rsqrtf(bnv[o] + LN_EPS) * bng[o];
            ta = sv * (pw1[o * 2] * pos[l * 2] + pw1[o * 2 + 1] * pos[l * 2 + 1]);
            ta2 = ta + (pb1[o] - bnm[o]) * sv + bnb[o];
        }
        sTa[o * 128 + t] = ta; sTa2[o * 128 + t] = ta2;
    }
    for (int r = 0; r < 2; r++) {
        const int e = tid + r * 256, h = e >> 5, o = e & 31;
        sW[e] = (h < 8 && o < 16) ? f2bf(pw2[h * 16 + o]) : (u16)0;
    }
    __syncthreads();
    const bf16x8 af = *(const bf16x8*)&sW[l16 * 32 + quad * 8];
    float uo[8][8];
    #pragma unroll
    for (int c = 0; c < 8; c++)
        #pragma unroll
        for (int j = 0; j < 8; j++)
            uo[c][j] = sTa[(quad * 8 + j) * 128 + c * 16 + l16];
    const f32x4 z4 = {0.f, 0.f, 0.f, 0.f};
    u16* outb = Bg + (size_t)n * 131072;  // 8*128*128
    for (int tl = 0; tl < 32; tl++) {
        const int t = wv * 32 + tl;
        float t2[8];
        #pragma unroll
        for (int j = 0; j < 8; j++) t2[j] = sTa2[(quad * 8 + j) * 128 + t];
        #pragma unroll
        for (int c = 0; c < 8; c++) {
            float rl[8];
            #pragma unroll
            for (int j = 0; j < 8; j++) rl[j] = fmaxf(t2[j] - uo[c][j], 0.f);
            union { unsigned u[4]; bf16x8 v; } bb;
            #pragma unroll
            for (int p = 0; p < 4; p++) bb.u[p] = pack2(rl[2 * p + 1], rl[2 * p]);
            const f32x4 cc = __builtin_amdgcn_mfma_f32_16x16x32_bf16(af, bb.v, z4, 0, 0, 0);
            if (quad < 2) {
                #pragma unroll
                for (int r = 0; r < 4; r++)
                    sOut[wv][(quad * 4 + r) * 128 + c * 16 + l16] =
                        (u16)(__float_as_uint(cc[r]) >> 16);
            }
        }
        // coalesced flush: 8 h-rows x 256B (wave-local, ds ordering within wave)
        #pragma unroll
        for (int it = 0; it < 2; it++) {
            const int idx = it * 64 + ln;
            const int h = idx >> 4, u8 = idx & 15;
            *(uint4*)(outb + (size_t)h * 16384 + t * 128 + u8 * 8) = *(const uint4*)&sOut[wv][idx * 8];
        }
    }
}

// ------------- windowed attention, one block per (window, head) -------------
__global__ __launch_bounds__(256, 2) void attn_k(
    const u16* __restrict__ Qkv, const u16* __restrict__ Bg, u16* __restrict__ Ob) {
    constexpr int SPS = 136;
    __shared__ alignas(16) u16 sQ[128 * 32];
    __shared__ alignas(16) u16 sK[128 * 32];
    __shared__ alignas(16) u16 sVt[32 * 128];
    __shared__ alignas(16) u16 sPB[128 * SPS];  // bias tile (stride 128), then P (stride 136)

    const int n = blockIdx.x, h = blockIdx.y;
    const int tid = threadIdx.x, wv = tid >> 6, ln = tid & 63;
    const int quad = ln >> 4, l16 = ln & 15;
    const int wh = n >> 4, ww = n & 15;

    {
        const int tb = wv * 16 + (ln >> 2);
        const int d8 = ln & 3;
        #pragma unroll
        for (int i = 0; i < 2; i++) {
            const int tt = tb + i * 64;
            const int l = (wh * 4 + (tt >> 5)) * 512 + ww * 32 + (tt & 31);
            const size_t g = (size_t)l * 768 + h * 32 + d8 * 8;
            async16(Qkv + g, &sQ[(wv * 16 + i * 64) * 32]);
            async16(Qkv + g + 256, &sK[(wv * 16 + i * 64) * 32]);
        }
        const u16* bsrc = Bg + (size_t)(n * 8 + h) * 16384;
        #pragma unroll
        for (int rr = 0; rr < 8; rr++)
            async16(bsrc + rr * 2048 + wv * 512 + ln * 8, &sPB[rr * 2048 + wv * 512]);
        #pragma unroll
        for (int i = 0; i < 2; i++) {
            const int tt = tb + i * 64;
            const int l = (wh * 4 + (tt >> 5)) * 512 + ww * 32 + (tt & 31);
            const uint4 raw = *(const uint4*)(Qkv + (size_t)l * 768 + 512 + h * 32 + d8 * 8);
            const u16* e = (const u16*)&raw;
            #pragma unroll
            for (int j = 0; j < 8; j++) sVt[(d8 * 8 + j) * 128 + tt] = e[j];
        }
    }
    __syncthreads();

    const f32x4 z4 = {0.f, 0.f, 0.f, 0.f};
    f32x4 acc[2][8];
    {
        bf16x8 qf[2], kf[8];
        #pragma unroll
        for (int i = 0; i < 2; i++) qf[i] = *(const bf16x8*)&sQ[(wv * 32 + i * 16 + l16) * 32 + quad * 8];
        #pragma unroll
        for (int j = 0; j < 8; j++) kf[j] = *(const bf16x8*)&sK[(j * 16 + l16) * 32 + quad * 8];
        #pragma unroll
        for (int i = 0; i < 2; i++)
            #pragma unroll
            for (int j = 0; j < 8; j++)
                acc[i][j] = __builtin_amdgcn_mfma_f32_16x16x32_bf16(qf[i], kf[j], z4, 0, 0, 0);
    }
    #pragma unroll
    for (int i = 0; i < 2; i++)
        #pragma unroll
        for (int j = 0; j < 8; j++)
            #pragma unroll
            for (int r = 0; r < 4; r++) {
                const int t = wv * 32 + i * 16 + quad * 4 + r;
                const unsigned bu = sPB[t * 128 + j * 16 + l16];
                acc[i][j][r] += __uint_as_float(bu << 16);
            }
    float rinv[2][4];
    #pragma unroll
    for (int i = 0; i < 2; i++) {
        #pragma unroll
        for (int r = 0; r < 4; r++) {
            float mx = acc[i][0][r];
            #pragma unroll
            for (int j = 1; j < 8; j++) mx = fmaxf(mx, acc[i][j][r]);
            #pragma unroll
            for (int m = 1; m < 16; m <<= 1) mx = fmaxf(mx, __shfl_xor(mx, m, 64));
            float sm = 0.f;
            #pragma unroll
            for (int j = 0; j < 8; j++) {
                const float p = __expf(acc[i][j][r] - mx);
                acc[i][j][r] = p;
                sm += p;
            }
            #pragma unroll
            for (int m = 1; m < 16; m <<= 1) sm += __shfl_xor(sm, m, 64);
            rinv[i][r] = 1.f / sm;
        }
    }
    __syncthreads();
    #pragma unroll
    for (int i = 0; i < 2; i++)
        #pragma unroll
        for (int j = 0; j < 8; j++)
            #pragma unroll
            for (int r = 0; r < 4; r++) {
                const int t = wv * 32 + i * 16 + quad * 4 + r;
                sPB[t * SPS + j * 16 + l16] = (u16)(__float_as_uint(acc[i][j][r]) >> 16);
            }
    __syncthreads();
    f32x4 oacc[2][2];
    #pragma unroll
    for (int i = 0; i < 2; i++)
        #pragma unroll
        for (int jd = 0; jd < 2; jd++) oacc[i][jd] = z4;
    #pragma unroll
    for (int ku = 0; ku < 4; ku++) {
        bf16x8 pf[2], vf[2];
        #pragma unroll
        for (int i = 0; i < 2; i++) pf[i] = *(const bf16x8*)&sPB[(wv * 32 + i * 16 + l16) * SPS + ku * 32 + quad * 8];
        #pragma unroll
        for (int jd = 0; jd < 2; jd++) vf[jd] = *(const bf16x8*)&sVt[(jd * 16 + l16) * 128 + ku * 32 + quad * 8];
        #pragma unroll
        for (int i = 0; i < 2; i++)
            #pragma unroll
            for (int jd = 0; jd < 2; jd++)
                oacc[i][jd] = __builtin_amdgcn_mfma_f32_16x16x32_bf16(pf[i], vf[jd], oacc[i][jd], 0, 0, 0);
    }
    #pragma unroll
    for (int i = 0; i < 2; i++)
        #pragma unroll
        for (int jd = 0; jd < 2; jd++)
            #pragma unroll
            for (int r = 0; r < 4; r++) {
                const int t = wv * 32 + i * 16 + quad * 4 + r;
                const int d = jd * 16 + l16;
                const int l = (wh * 4 + (t >> 5)) * 512 + ww * 32 + (t & 31);
                Ob[(size_t)l * 256 + h * 32 + d] = f2bf(oacc[i][jd][r] * rinv[i][r]);
            }
}

// ------------- fused MLP: out[m] += gelu(xn2[m]@fc1 + b1)@fc2 + b2  (H never hits HBM) -------------
// Weights staged through LDS via async16 (coalesced), fragments read from LDS (m97 pattern).
// LDS: sA 64x256 (32KB, staged once) + sW 32KB staging + sH 64x128 (16KB) = 80KB -> 2 blocks/CU.
__global__ __launch_bounds__(256, 2) void mlp_fused(
    const u16* __restrict__ Xn, const u16* __restrict__ fc1T, const u16* __restrict__ fc2T,
    const float* __restrict__ b1, const float* __restrict__ b2, float* __restrict__ Out) {
    __shared__ alignas(16) u16 sA[64 * 256];   // 32KB
    __shared__ alignas(16) u16 sW[128 * 128];  // 32KB staging: fc1 [128r x 128k] / fc2 [256r x 64k]
    __shared__ alignas(16) u16 sH[64 * 128];   // 16KB
    const int tid = threadIdx.x, wv = tid >> 6, ln = tid & 63;
    const int quad = ln >> 4, l16 = ln & 15;
    const int m0 = blockIdx.x * 64;
    const int mw = (wv >> 1) * 32;         // 2-way M split
    const int nw1 = (wv & 1) * 64;         // fc1 N split (128 cols)
    const int nw2 = (wv & 1) * 128;        // fc2 N split (256 cols)

    // stage A once: 64 rows x 512B, each async16 instr covers 2 rows (1KB)
    #pragma unroll
    for (int rr = 0; rr < 8; rr++) {
        const int row = rr * 8 + wv * 2 + (ln >> 5);
        async16(Xn + (size_t)(m0 + row) * 256 + (ln & 31) * 8, &sA[(rr * 8 + wv * 2) * 256]);
    }

    const f32x4 z4 = {0.f, 0.f, 0.f, 0.f};
    f32x4 acc2[2][8];
    #pragma unroll
    for (int i = 0; i < 2; i++)
        #pragma unroll
        for (int j = 0; j < 8; j++) acc2[i][j] = z4;

    for (int c = 0; c < 8; c++) {
        // ---- fc1: C1[64x128] for H-cols c*128..+127, K=256 in 2 chunks of 128 ----
        f32x4 acc1[2][4];
        #pragma unroll
        for (int i = 0; i < 2; i++)
            #pragma unroll
            for (int j = 0; j < 4; j++) acc1[i][j] = z4;
        #pragma unroll
        for (int kc0 = 0; kc0 < 2; kc0++) {
            __syncthreads();  // prior reads of sW (and first-iter sA staging) done
            // stage fc1T rows [c*128, +128) x k [kc0*128, +128): row=256B, 4 rows per instr
            #pragma unroll
            for (int rr = 0; rr < 8; rr++) {
                const int r0 = wv * 32 + rr * 4;
                async16(fc1T + (size_t)(c * 128 + r0 + (ln >> 4)) * 256 + kc0 * 128 + (ln & 15) * 8,
                        &sW[r0 * 128]);
            }
            __syncthreads();
            #pragma unroll
            for (int kk = 0; kk < 4; kk++) {
                bf16x8 af[2], bfr[4];
                #pragma unroll
                for (int i = 0; i < 2; i++)
                    af[i] = *(const bf16x8*)&sA[(mw + i * 16 + l16) * 256 + kc0 * 128 + kk * 32 + quad * 8];
                #pragma unroll
                for (int j = 0; j < 4; j++)
                    bfr[j] = *(const bf16x8*)&sW[(nw1 + j * 16 + l16) * 128 + kk * 32 + quad * 8];
                #pragma unroll
                for (int i = 0; i < 2; i++)
                    #pragma unroll
                    for (int j = 0; j < 4; j++)
                        acc1[i][j] = __builtin_amdgcn_mfma_f32_16x16x32_bf16(af[i], bfr[j], acc1[i][j], 0, 0, 0);
            }
        }
        // ---- gelu -> sH ----
        #pragma unroll
        for (int j = 0; j < 4; j++) {
            const float bc = b1[c * 128 + nw1 + j * 16 + l16];
            #pragma unroll
            for (int i = 0; i < 2; i++)
                #pragma unroll
                for (int r = 0; r < 4; r++) {
                    float v = acc1[i][j][r] + bc;
                    const float p = v * v;
                    const float qq = fmaf(p, -0.07135481283f, -1.5957691216f);
                    v = v / (1.f + __expf(v * qq));  // gelu approx
                    sH[(mw + i * 16 + quad * 4 + r) * 128 + nw1 + j * 16 + l16] = f2bf(v);
                }
        }
        // ---- fc2 accumulate: K-chunk = H cols c*128..+127, 2 chunks of 64 ----
        #pragma unroll
        for (int kc0 = 0; kc0 < 2; kc0++) {
            __syncthreads();  // sH complete (kc0=0) / prior sW reads done
            // stage fc2T rows [0,256) x k [c*128+kc0*64, +64): row=128B, 8 rows per instr
            #pragma unroll
            for (int rr = 0; rr < 8; rr++) {
                const int r0 = wv * 64 + rr * 8;
                async16(fc2T + (size_t)(r0 + (ln >> 3)) * 1024 + c * 128 + kc0 * 64 + (ln & 7) * 8,
                        &sW[r0 * 64]);
            }
            __syncthreads();
            #pragma unroll
            for (int kk = 0; kk < 2; kk++) {
                bf16x8 pf[2], bfr[8];
                #pragma unroll
                for (int i = 0; i < 2; i++)
                    pf[i] = *(const bf16x8*)&sH[(mw + i * 16 + l16) * 128 + kc0 * 64 + kk * 32 + quad * 8];
                #pragma unroll
                for (int j = 0; j < 8; j++)
                    bfr[j] = *(const bf16x8*)&sW[(nw2 + j * 16 + l16) * 64 + kk * 32 + quad * 8];
                #pragma unroll
                for (int i = 0; i < 2; i++)
                    #pragma unroll
                    for (int j = 0; j < 8; j++)
                        acc2[i][j] = __builtin_amdgcn_mfma_f32_16x16x32_bf16(pf[i], bfr[j], acc2[i][j], 0, 0, 0);
            }
        }
    }
    // epilogue: out = acc2 + b2 + out (residual, in-place)
    #pragma unroll
    for (int j = 0; j < 8; j++) {
        const int col = nw2 + j * 16 + l16;
        const float bc = b2[col];
        #pragma unroll
        for (int i = 0; i < 2; i++)
            #pragma unroll
            for (int r = 0; r < 4; r++) {
                const size_t idx = (size_t)(m0 + mw + i * 16 + quad * 4 + r) * 256 + col;
                Out[idx] = acc2[i][j][r] + bc + Out[idx];
            }
    }
}

extern "C" void kernel_launch(void* const* d_in, const int* in_sizes, int n_in,
                              void* d_out, int out_size, void* d_ws, size_t ws_size,
                              hipStream_t stream) {
    const float* x    = (const float*)d_in[0];
    const float* pos  = (const float*)d_in[1];
    const float* n1g  = (const float*)d_in[2];
    const float* n1b  = (const float*)d_in[3];
    const float* wq   = (const float*)d_in[4];
    const float* bq   = (const float*)d_in[5];
    const float* wk   = (const float*)d_in[6];
    const float* bk   = (const float*)d_in[7];
    const float* wvw  = (const float*)d_in[8];
    const float* bv   = (const float*)d_in[9];
    const float* wo   = (const float*)d_in[10];
    const float* bo   = (const float*)d_in[11];
    const float* n2g  = (const float*)d_in[12];
    const float* n2b  = (const float*)d_in[13];
    const float* wfc1 = (const float*)d_in[14];
    const float* bfc1 = (const float*)d_in[15];
    const float* wfc2 = (const float*)d_in[16];
    const float* bfc2 = (const float*)d_in[17];
    const float* pw1  = (const float*)d_in[18];
    const float* pb1  = (const float*)d_in[19];
    const float* bng  = (const float*)d_in[20];
    const float* bnb  = (const float*)d_in[21];
    const float* bnm  = (const float*)d_in[22];
    const float* bnv  = (const float*)d_in[23];
    const float* pw2  = (const float*)d_in[24];
    float* out = (float*)d_out;
    u16* ws  = (u16*)d_ws;

    const size_t SZ = (size_t)32768 * 256;  // one [L,C] bf16 slot
    u16* s0   = ws;                // xn -> O -> xn2
    u16* qkv  = ws + SZ;           // packed [L][768] QKV (3 slots)
    u16* wqT  = ws + 4 * SZ;       // q,k,v transposed weights CONTIGUOUS -> fused Wt
    u16* wkT  = wqT + 65536;
    u16* wvT  = wkT + 65536;
    u16* woT  = wvT + 65536;
    u16* fc1T = woT + 65536;
    u16* fc2T = fc1T + 262144;
    u16* biasg = fc2T + 262144;    // 256*8*128*128 bf16 = 67 MB

    transpose_all<<<768, dim3(32, 8), 0, stream>>>(wq, wk, wvw, wo, wfc1, wfc2,
                                                   wqT, wkT, wvT, woT, fc1T, fc2T);
    ln_k<<<8192, 256, 0, stream>>>(x, n1g, n1b, s0);
    // fused QKV projection: [32768,256] x [768,256]^T -> packed [32768,768]
    gemm_bt<<<dim3(6, 256), 256, 0, stream>>>(s0, wqT, bq, bk, bv, nullptr, qkv, nullptr,
                                              32768, 768, 256, 4);
    bias_k<<<256, 256, 0, stream>>>(pos, pw1, pb1, bng, bnb, bnm, bnv, pw2, biasg);
    attn_k<<<dim3(256, 8), 256, 0, stream>>>(qkv, biasg, s0);
    // X1 = x + O@wo + bo -> d_out (fp32)
    gemm_bt<<<dim3(2, 256), 256, 0, stream>>>(s0, woT, bo, nullptr, nullptr, x, nullptr, out,
                                              32768, 256, 256, 2);
    ln_k<<<8192, 256, 0, stream>>>(out, n2g, n2b, s0);
    // fused MLP: out += gelu(xn2@fc1+b1)@fc2+b2, H stays on-chip
    mlp_fused<<<512, 256, 0, stream>>>(s0, fc1T, fc2T, bfc1, bfc2, out);
}

// Round 6
// 322.367 us; speedup vs baseline: 1.3633x; 1.1307x over previous
//
#include <hip/hip_runtime.h>
#include <cstdint>

typedef unsigned short u16;
typedef __bf16 bf16x8 __attribute__((ext_vector_type(8)));
typedef float f32x4 __attribute__((ext_vector_type(4)));

#define LN_EPS 1e-5f
#define SCALE_Q 0.17677669529663689f  // 32^-0.5

__device__ __forceinline__ u16 f2bf(float f) {
    union { float f; unsigned int i; } c; c.f = f;
    unsigned int r = c.i + 0x7FFFu + ((c.i >> 16) & 1u);
    return (u16)(r >> 16);
}
// pack two f32 -> two bf16 (truncation) in one v_perm_b32
__device__ __forceinline__ unsigned pack2(float hi, float lo) {
    return __builtin_amdgcn_perm(__float_as_uint(hi), __float_as_uint(lo), 0x07060302u);
}
// async global->LDS, 16B per lane; lds pointer must be wave-uniform
__device__ __forceinline__ void async16(const void* g, void* l) {
    __builtin_amdgcn_global_load_lds(
        (__attribute__((address_space(1))) unsigned int*)(unsigned long long)g,
        (__attribute__((address_space(3))) unsigned int*)l, 16, 0, 0);
}

// ------------- all 6 weight transposes (+bf16 cast) in one dispatch -------------
__global__ void transpose_all(const float* __restrict__ wq, const float* __restrict__ wk,
                              const float* __restrict__ wv, const float* __restrict__ wo,
                              const float* __restrict__ f1, const float* __restrict__ f2,
                              u16* oq, u16* ok, u16* ov, u16* oo, u16* o1, u16* o2) {
    __shared__ float tile[32][33];
    const int b = blockIdx.x;
    const float* In; u16* Out; int R, C, bx, by;
    if (b < 256) {
        const int m = b >> 6, l = b & 63;
        In = m == 0 ? wq : (m == 1 ? wk : (m == 2 ? wv : wo));
        Out = m == 0 ? oq : (m == 1 ? ok : (m == 2 ? ov : oo));
        R = 256; C = 256; bx = (l & 7) * 32; by = (l >> 3) * 32;
    } else if (b < 512) {
        const int l = b - 256; In = f1; Out = o1; R = 256; C = 1024;
        bx = (l & 31) * 32; by = (l >> 5) * 32;
    } else {
        const int l = b - 512; In = f2; Out = o2; R = 1024; C = 256;
        bx = (l & 7) * 32; by = (l >> 3) * 32;
    }
    const int tx = threadIdx.x, ty = threadIdx.y;
    for (int i = 0; i < 32; i += 8)
        tile[ty + i][tx] = In[(size_t)(by + ty + i) * C + bx + tx];
    __syncthreads();
    for (int i = 0; i < 32; i += 8)
        Out[(size_t)(bx + ty + i) * R + by + tx] = f2bf(tile[tx][ty + i]);
}

// ------------- LayerNorm: one wave per token (C=256); fp32 in -> bf16 out -------------
__global__ __launch_bounds__(256) void ln_k(const float* __restrict__ X, const float* __restrict__ G,
                                            const float* __restrict__ Bt, u16* __restrict__ Y) {
    const int token = blockIdx.x * 4 + (threadIdx.x >> 6);
    const int ln = threadIdx.x & 63;
    const float4 rv = *(const float4*)(X + (size_t)token * 256 + ln * 4);
    float s = rv.x + rv.y + rv.z + rv.w;
    float q = rv.x * rv.x + rv.y * rv.y + rv.z * rv.z + rv.w * rv.w;
    #pragma unroll
    for (int m = 1; m < 64; m <<= 1) { s += __shfl_xor(s, m, 64); q += __shfl_xor(q, m, 64); }
    const float mean = s * (1.f / 256.f);
    const float var  = q * (1.f / 256.f) - mean * mean;
    const float rs   = rsqrtf(var + LN_EPS);
    const float4 gv = *(const float4*)(G + ln * 4);
    const float4 bv = *(const float4*)(Bt + ln * 4);
    ushort4 o;
    o.x = f2bf((rv.x - mean) * rs * gv.x + bv.x);
    o.y = f2bf((rv.y - mean) * rs * gv.y + bv.y);
    o.z = f2bf((rv.z - mean) * rs * gv.z + bv.z);
    o.w = f2bf((rv.w - mean) * rs * gv.w + bv.w);
    *(ushort4*)(Y + (size_t)token * 256 + ln * 4) = o;
}

// ------------- GEMM (B^T form): Y[m,n] = sum_k X[m,k]*Wt[n,k] + epilogue -------------
// mode: 2 = +bias + Res[m,n] (fp32 out) ; 4 = fused-QKV (seg bias, Q scaled, bf16 out)
__global__ __launch_bounds__(256, 2) void gemm_bt(
    const u16* __restrict__ X, const u16* __restrict__ Wt,
    const float* __restrict__ B1, const float* __restrict__ B2, const float* __restrict__ B3,
    const float* __restrict__ Res,
    u16* __restrict__ Ybf, float* __restrict__ Yf,
    int M, int N, int K, int mode) {
    __shared__ alignas(16) u16 sBuf[128 * 128];  // K-loop: sA=sBuf, sB=sBuf+8192; epilogue: C tile
    u16* sA = sBuf;
    u16* sB = sBuf + 128 * 64;
    const int tid = threadIdx.x, wv = tid >> 6, ln = tid & 63;
    const int quad = ln >> 4, l16 = ln & 15;
    const int m0 = blockIdx.y * 128, n0 = blockIdx.x * 128;
    const int mw = (wv >> 1) * 64, nw = (wv & 1) * 64;
    const int r8 = ln >> 3, c8 = ln & 7;
    const f32x4 z4 = {0.f, 0.f, 0.f, 0.f};
    f32x4 acc[4][4];
    #pragma unroll
    for (int i = 0; i < 4; i++)
        #pragma unroll
        for (int j = 0; j < 4; j++) acc[i][j] = z4;

    for (int k0 = 0; k0 < K; k0 += 64) {
        __syncthreads();
        #pragma unroll
        for (int i = 0; i < 4; i++) {
            const int row = wv * 32 + i * 8;
            async16(X  + (size_t)(m0 + row + r8) * K + k0 + c8 * 8, &sA[row * 64]);
            async16(Wt + (size_t)(n0 + row + r8) * K + k0 + c8 * 8, &sB[row * 64]);
        }
        __syncthreads();
        #pragma unroll
        for (int kk = 0; kk < 2; kk++) {
            bf16x8 af[4], bfr[4];
            #pragma unroll
            for (int i = 0; i < 4; i++) af[i]  = *(const bf16x8*)&sA[(mw + i * 16 + l16) * 64 + kk * 32 + quad * 8];
            #pragma unroll
            for (int j = 0; j < 4; j++) bfr[j] = *(const bf16x8*)&sB[(nw + j * 16 + l16) * 64 + kk * 32 + quad * 8];
            #pragma unroll
            for (int i = 0; i < 4; i++)
                #pragma unroll
                for (int j = 0; j < 4; j++)
                    acc[i][j] = __builtin_amdgcn_mfma_f32_16x16x32_bf16(af[i], bfr[j], acc[i][j], 0, 0, 0);
        }
    }
    // epilogue
    const int seg = n0 >> 8;  // for mode 4 (block fully inside one 256-col segment)
    const float* bp = (mode == 4) ? (seg == 0 ? B1 : (seg == 1 ? B2 : B3)) : B1;
    const float sc = (mode == 4 && seg == 0) ? SCALE_Q : 1.f;
    if (mode == 4) {
        __syncthreads();  // done with sA/sB staging reads
        #pragma unroll
        for (int j = 0; j < 4; j++) {
            const int col = nw + j * 16 + l16;
            const float bc = bp[(n0 + col) & 255];
            #pragma unroll
            for (int i = 0; i < 4; i++)
                #pragma unroll
                for (int r = 0; r < 4; r++)
                    sBuf[(mw + i * 16 + quad * 4 + r) * 128 + col] = f2bf((acc[i][j][r] + bc) * sc);
        }
        __syncthreads();
        // coalesced stores: 128 rows x 256B
        #pragma unroll
        for (int it = 0; it < 8; it++) {
            const int idx = it * 256 + tid;
            const int row = idx >> 4, sg = idx & 15;
            *(uint4*)(Ybf + (size_t)(m0 + row) * N + n0 + sg * 8) = *(const uint4*)&sBuf[row * 128 + sg * 8];
        }
    } else {
        #pragma unroll
        for (int j = 0; j < 4; j++) {
            const int col = n0 + nw + j * 16 + l16;
            const float bc = bp[col];
            #pragma unroll
            for (int i = 0; i < 4; i++) {
                #pragma unroll
                for (int r = 0; r < 4; r++) {
                    const int row = m0 + mw + i * 16 + quad * 4 + r;
                    float v = acc[i][j][r] + bc;
                    if (mode == 2) v += Res[(size_t)row * N + col];
                    Yf[(size_t)row * N + col] = v;
                }
            }
        }
    }
}

// ------------- per-window bias: bias[h][t][u] = sum_o pw2[h][o]*relu(ta2[o][t]-ta[o][u]) -------------
__global__ __launch_bounds__(256) void bias_k(
    const float* __restrict__ pos, const float* __restrict__ pw1, const float* __restrict__ pb1,
    const float* __restrict__ bng, const float* __restrict__ bnb, const float* __restrict__ bnm,
    const float* __restrict__ bnv, const float* __restrict__ pw2, u16* __restrict__ Bg) {
    __shared__ float sTa[32 * 128], sTa2[32 * 128];  // o padded 16->32 with zeros
    __shared__ u16 sW[16 * 32];
    __shared__ alignas(16) u16 sOut[4][8 * 128];     // per-wave [h][u] staging for one t
    const int n = blockIdx.x, wh = n >> 4, ww = n & 15;
    const int tid = threadIdx.x, wv = tid >> 6, ln = tid & 63;
    const int quad = ln >> 4, l16 = ln & 15;
    for (int r = 0; r < 16; r++) {
        const int e = tid + r * 256, o = e >> 7, t = e & 127;
        float ta = 0.f, ta2 = 0.f;
        if (o < 16) {
            const int l = (wh * 4 + (t >> 5)) * 512 + ww * 32 + (t & 31);
            const float sv = rsqrtf(bnv[o] + LN_EPS) * bng[o];
            ta = sv * (pw1[o * 2] * pos[l * 2] + pw1[o * 2 + 1] * pos[l * 2 + 1]);
            ta2 = ta + (pb1[o] - bnm[o]) * sv + bnb[o];
        }
        sTa[o * 128 + t] = ta; sTa2[o * 128 + t] = ta2;
    }
    for (int r = 0; r < 2; r++) {
        const int e = tid + r * 256, h = e >> 5, o = e & 31;
        sW[e] = (h < 8 && o < 16) ? f2bf(pw2[h * 16 + o]) : (u16)0;
    }
    __syncthreads();
    const bf16x8 af = *(const bf16x8*)&sW[l16 * 32 + quad * 8];
    float uo[8][8];
    #pragma unroll
    for (int c = 0; c < 8; c++)
        #pragma unroll
        for (int j = 0; j < 8; j++)
            uo[c][j] = sTa[(quad * 8 + j) * 128 + c * 16 + l16];
    const f32x4 z4 = {0.f, 0.f, 0.f, 0.f};
    u16* outb = Bg + (size_t)n * 131072;  // 8*128*128
    for (int tl = 0; tl < 32; tl++) {
        const int t = wv * 32 + tl;
        float t2[8];
        #pragma unroll
        for (int j = 0; j < 8; j++) t2[j] = sTa2[(quad * 8 + j) * 128 + t];
        #pragma unroll
        for (int c = 0; c < 8; c++) {
            float rl[8];
            #pragma unroll
            for (int j = 0; j < 8; j++) rl[j] = fmaxf(t2[j] - uo[c][j], 0.f);
            union { unsigned u[4]; bf16x8 v; } bb;
            #pragma unroll
            for (int p = 0; p < 4; p++) bb.u[p] = pack2(rl[2 * p + 1], rl[2 * p]);
            const f32x4 cc = __builtin_amdgcn_mfma_f32_16x16x32_bf16(af, bb.v, z4, 0, 0, 0);
            if (quad < 2) {
                #pragma unroll
                for (int r = 0; r < 4; r++)
                    sOut[wv][(quad * 4 + r) * 128 + c * 16 + l16] =
                        (u16)(__float_as_uint(cc[r]) >> 16);
            }
        }
        // coalesced flush: 8 h-rows x 256B (wave-local, ds ordering within wave)
        #pragma unroll
        for (int it = 0; it < 2; it++) {
            const int idx = it * 64 + ln;
            const int h = idx >> 4, u8 = idx & 15;
            *(uint4*)(outb + (size_t)h * 16384 + t * 128 + u8 * 8) = *(const uint4*)&sOut[wv][idx * 8];
        }
    }
}

// ------------- windowed attention, one block per (window, head) -------------
__global__ __launch_bounds__(256, 2) void attn_k(
    const u16* __restrict__ Qkv, const u16* __restrict__ Bg, u16* __restrict__ Ob) {
    constexpr int SPS = 136;
    __shared__ alignas(16) u16 sQ[128 * 32];
    __shared__ alignas(16) u16 sK[128 * 32];
    __shared__ alignas(16) u16 sVt[32 * 128];
    __shared__ alignas(16) u16 sPB[128 * SPS];  // bias tile (stride 128), then P (stride 136)

    const int n = blockIdx.x, h = blockIdx.y;
    const int tid = threadIdx.x, wv = tid >> 6, ln = tid & 63;
    const int quad = ln >> 4, l16 = ln & 15;
    const int wh = n >> 4, ww = n & 15;

    {
        const int tb = wv * 16 + (ln >> 2);
        const int d8 = ln & 3;
        #pragma unroll
        for (int i = 0; i < 2; i++) {
            const int tt = tb + i * 64;
            const int l = (wh * 4 + (tt >> 5)) * 512 + ww * 32 + (tt & 31);
            const size_t g = (size_t)l * 768 + h * 32 + d8 * 8;
            async16(Qkv + g, &sQ[(wv * 16 + i * 64) * 32]);
            async16(Qkv + g + 256, &sK[(wv * 16 + i * 64) * 32]);
        }
        const u16* bsrc = Bg + (size_t)(n * 8 + h) * 16384;
        #pragma unroll
        for (int rr = 0; rr < 8; rr++)
            async16(bsrc + rr * 2048 + wv * 512 + ln * 8, &sPB[rr * 2048 + wv * 512]);
        #pragma unroll
        for (int i = 0; i < 2; i++) {
            const int tt = tb + i * 64;
            const int l = (wh * 4 + (tt >> 5)) * 512 + ww * 32 + (tt & 31);
            const uint4 raw = *(const uint4*)(Qkv + (size_t)l * 768 + 512 + h * 32 + d8 * 8);
            const u16* e = (const u16*)&raw;
            #pragma unroll
            for (int j = 0; j < 8; j++) sVt[(d8 * 8 + j) * 128 + tt] = e[j];
        }
    }
    __syncthreads();

    const f32x4 z4 = {0.f, 0.f, 0.f, 0.f};
    f32x4 acc[2][8];
    {
        bf16x8 qf[2], kf[8];
        #pragma unroll
        for (int i = 0; i < 2; i++) qf[i] = *(const bf16x8*)&sQ[(wv * 32 + i * 16 + l16) * 32 + quad * 8];
        #pragma unroll
        for (int j = 0; j < 8; j++) kf[j] = *(const bf16x8*)&sK[(j * 16 + l16) * 32 + quad * 8];
        #pragma unroll
        for (int i = 0; i < 2; i++)
            #pragma unroll
            for (int j = 0; j < 8; j++)
                acc[i][j] = __builtin_amdgcn_mfma_f32_16x16x32_bf16(qf[i], kf[j], z4, 0, 0, 0);
    }
    #pragma unroll
    for (int i = 0; i < 2; i++)
        #pragma unroll
        for (int j = 0; j < 8; j++)
            #pragma unroll
            for (int r = 0; r < 4; r++) {
                const int t = wv * 32 + i * 16 + quad * 4 + r;
                const unsigned bu = sPB[t * 128 + j * 16 + l16];
                acc[i][j][r] += __uint_as_float(bu << 16);
            }
    float rinv[2][4];
    #pragma unroll
    for (int i = 0; i < 2; i++) {
        #pragma unroll
        for (int r = 0; r < 4; r++) {
            float mx = acc[i][0][r];
            #pragma unroll
            for (int j = 1; j < 8; j++) mx = fmaxf(mx, acc[i][j][r]);
            #pragma unroll
            for (int m = 1; m < 16; m <<= 1) mx = fmaxf(mx, __shfl_xor(mx, m, 64));
            float sm = 0.f;
            #pragma unroll
            for (int j = 0; j < 8; j++) {
                const float p = __expf(acc[i][j][r] - mx);
                acc[i][j][r] = p;
                sm += p;
            }
            #pragma unroll
            for (int m = 1; m < 16; m <<= 1) sm += __shfl_xor(sm, m, 64);
            rinv[i][r] = 1.f / sm;
        }
    }
    __syncthreads();
    #pragma unroll
    for (int i = 0; i < 2; i++)
        #pragma unroll
        for (int j = 0; j < 8; j++)
            #pragma unroll
            for (int r = 0; r < 4; r++) {
                const int t = wv * 32 + i * 16 + quad * 4 + r;
                sPB[t * SPS + j * 16 + l16] = (u16)(__float_as_uint(acc[i][j][r]) >> 16);
            }
    __syncthreads();
    f32x4 oacc[2][2];
    #pragma unroll
    for (int i = 0; i < 2; i++)
        #pragma unroll
        for (int jd = 0; jd < 2; jd++) oacc[i][jd] = z4;
    #pragma unroll
    for (int ku = 0; ku < 4; ku++) {
        bf16x8 pf[2], vf[2];
        #pragma unroll
        for (int i = 0; i < 2; i++) pf[i] = *(const bf16x8*)&sPB[(wv * 32 + i * 16 + l16) * SPS + ku * 32 + quad * 8];
        #pragma unroll
        for (int jd = 0; jd < 2; jd++) vf[jd] = *(const bf16x8*)&sVt[(jd * 16 + l16) * 128 + ku * 32 + quad * 8];
        #pragma unroll
        for (int i = 0; i < 2; i++)
            #pragma unroll
            for (int jd = 0; jd < 2; jd++)
                oacc[i][jd] = __builtin_amdgcn_mfma_f32_16x16x32_bf16(pf[i], vf[jd], oacc[i][jd], 0, 0, 0);
    }
    #pragma unroll
    for (int i = 0; i < 2; i++)
        #pragma unroll
        for (int jd = 0; jd < 2; jd++)
            #pragma unroll
            for (int r = 0; r < 4; r++) {
                const int t = wv * 32 + i * 16 + quad * 4 + r;
                const int d = jd * 16 + l16;
                const int l = (wh * 4 + (t >> 5)) * 512 + ww * 32 + (t & 31);
                Ob[(size_t)l * 256 + h * 32 + d] = f2bf(oacc[i][jd][r] * rinv[i][r]);
            }
}

// ------------- fused MLP: out[m] += gelu(xn2[m]@fc1 + b1)@fc2 + b2  (H never hits HBM) -------------
// All LDS tiles XOR-swizzled on 16B blocks (physical blk = logical blk ^ (row & mask)) to break
// the 16-way same-bank aliasing of power-of-2 row strides. Swizzle is baked into the per-lane
// global addresses of the async16 staging (lane fetches the block that belongs in its slot).
// LDS: sA 32KB + sW 32KB + sH 16KB = 80KB -> 2 blocks/CU.
__global__ __launch_bounds__(256, 2) void mlp_fused(
    const u16* __restrict__ Xn, const u16* __restrict__ fc1T, const u16* __restrict__ fc2T,
    const float* __restrict__ b1, const float* __restrict__ b2, float* __restrict__ Out) {
    __shared__ alignas(16) u16 sA[64 * 256];   // row stride 512B, swizzle mask 7  (32 blks/row)
    __shared__ alignas(16) u16 sW[128 * 128];  // fc1: 128r x 256B, mask 15 (16 blks) | fc2: 256r x 128B, mask 7 (8 blks)
    __shared__ alignas(16) u16 sH[64 * 128];   // row stride 256B, swizzle mask 15 (16 blks)
    const int tid = threadIdx.x, wv = tid >> 6, ln = tid & 63;
    const int quad = ln >> 4, l16 = ln & 15;
    const int m0 = blockIdx.x * 64;
    const int mw = (wv >> 1) * 32;         // 2-way M split
    const int nw1 = (wv & 1) * 64;         // fc1 N split (128 cols)
    const int nw2 = (wv & 1) * 128;        // fc2 N split (256 cols)

    // stage A once (swizzled): each async16 covers 2 rows; lane i -> row base+ (i>>5), phys blk i&31
    #pragma unroll
    for (int rr = 0; rr < 8; rr++) {
        const int row2 = rr * 8 + wv * 2;
        const int row = row2 + (ln >> 5);
        const int kb = (ln & 31) ^ (row & 7);   // logical k-block for this slot
        async16(Xn + (size_t)(m0 + row) * 256 + kb * 8, &sA[row2 * 256]);
    }

    const f32x4 z4 = {0.f, 0.f, 0.f, 0.f};
    f32x4 acc2[2][8];
    #pragma unroll
    for (int i = 0; i < 2; i++)
        #pragma unroll
        for (int j = 0; j < 8; j++) acc2[i][j] = z4;

    for (int c = 0; c < 8; c++) {
        // ---- fc1: C1[64x128] for H-cols c*128..+127, K=256 in 2 chunks of 128 ----
        f32x4 acc1[2][4];
        #pragma unroll
        for (int i = 0; i < 2; i++)
            #pragma unroll
            for (int j = 0; j < 4; j++) acc1[i][j] = z4;
        #pragma unroll
        for (int kc0 = 0; kc0 < 2; kc0++) {
            __syncthreads();  // prior reads of sW (and first-iter sA staging) done
            // stage fc1T rows [c*128,+128) x k [kc0*128,+128): 4 rows/instr, swizzled
            #pragma unroll
            for (int rr = 0; rr < 8; rr++) {
                const int r4 = wv * 32 + rr * 4;
                const int row = r4 + (ln >> 4);
                const int kb = (ln & 15) ^ (row & 15);
                async16(fc1T + (size_t)(c * 128 + row) * 256 + kc0 * 128 + kb * 8, &sW[r4 * 128]);
            }
            __syncthreads();
            #pragma unroll
            for (int kk = 0; kk < 4; kk++) {
                bf16x8 af[2], bfr[4];
                #pragma unroll
                for (int i = 0; i < 2; i++) {
                    const int ra = mw + i * 16 + l16;
                    const int b = kc0 * 16 + kk * 4 + quad;
                    af[i] = *(const bf16x8*)&sA[ra * 256 + ((b ^ (ra & 7)) * 8)];
                }
                #pragma unroll
                for (int j = 0; j < 4; j++) {
                    const int rb = nw1 + j * 16 + l16;
                    const int b = kk * 4 + quad;
                    bfr[j] = *(const bf16x8*)&sW[rb * 128 + ((b ^ (rb & 15)) * 8)];
                }
                #pragma unroll
                for (int i = 0; i < 2; i++)
                    #pragma unroll
                    for (int j = 0; j < 4; j++)
                        acc1[i][j] = __builtin_amdgcn_mfma_f32_16x16x32_bf16(af[i], bfr[j], acc1[i][j], 0, 0, 0);
            }
        }
        // ---- gelu -> sH (swizzled writes) ----
        #pragma unroll
        for (int j = 0; j < 4; j++) {
            const float bc = b1[c * 128 + nw1 + j * 16 + l16];
            const int col = nw1 + j * 16 + l16;
            const int blk = col >> 3, off = col & 7;
            #pragma unroll
            for (int i = 0; i < 2; i++)
                #pragma unroll
                for (int r = 0; r < 4; r++) {
                    float v = acc1[i][j][r] + bc;
                    const float p = v * v;
                    const float qq = fmaf(p, -0.07135481283f, -1.5957691216f);
                    v = v / (1.f + __expf(v * qq));  // gelu approx
                    const int row = mw + i * 16 + quad * 4 + r;
                    sH[row * 128 + ((blk ^ (row & 15)) * 8) + off] = f2bf(v);
                }
        }
        // ---- fc2 accumulate: K-chunk = H cols c*128..+127, 2 chunks of 64 ----
        #pragma unroll
        for (int kc0 = 0; kc0 < 2; kc0++) {
            __syncthreads();  // sH complete (kc0=0) / prior sW reads done
            // stage fc2T rows [0,256) x k [c*128+kc0*64,+64): 8 rows/instr, swizzled
            #pragma unroll
            for (int rr = 0; rr < 8; rr++) {
                const int r8 = wv * 64 + rr * 8;
                const int row = r8 + (ln >> 3);
                const int kb = (ln & 7) ^ (row & 7);
                async16(fc2T + (size_t)row * 1024 + c * 128 + kc0 * 64 + kb * 8, &sW[r8 * 64]);
            }
            __syncthreads();
            #pragma unroll
            for (int kk = 0; kk < 2; kk++) {
                bf16x8 pf[2], bfr[8];
                #pragma unroll
                for (int i = 0; i < 2; i++) {
                    const int rp = mw + i * 16 + l16;
                    const int b = kc0 * 8 + kk * 4 + quad;  // logical blk in full sH row
                    pf[i] = *(const bf16x8*)&sH[rp * 128 + ((b ^ (rp & 15)) * 8)];
                }
                #pragma unroll
                for (int j = 0; j < 8; j++) {
                    const int rb = nw2 + j * 16 + l16;
                    const int b = kk * 4 + quad;
                    bfr[j] = *(const bf16x8*)&sW[rb * 64 + ((b ^ (rb & 7)) * 8)];
                }
                #pragma unroll
                for (int i = 0; i < 2; i++)
                    #pragma unroll
                    for (int j = 0; j < 8; j++)
                        acc2[i][j] = __builtin_amdgcn_mfma_f32_16x16x32_bf16(pf[i], bfr[j], acc2[i][j], 0, 0, 0);
            }
        }
    }
    // epilogue: out = acc2 + b2 + out (residual, in-place)
    #pragma unroll
    for (int j = 0; j < 8; j++) {
        const int col = nw2 + j * 16 + l16;
        const float bc = b2[col];
        #pragma unroll
        for (int i = 0; i < 2; i++)
            #pragma unroll
            for (int r = 0; r < 4; r++) {
                const size_t idx = (size_t)(m0 + mw + i * 16 + quad * 4 + r) * 256 + col;
                Out[idx] = acc2[i][j][r] + bc + Out[idx];
            }
    }
}

extern "C" void kernel_launch(void* const* d_in, const int* in_sizes, int n_in,
                              void* d_out, int out_size, void* d_ws, size_t ws_size,
                              hipStream_t stream) {
    const float* x    = (const float*)d_in[0];
    const float* pos  = (const float*)d_in[1];
    const float* n1g  = (const float*)d_in[2];
    const float* n1b  = (const float*)d_in[3];
    const float* wq   = (const float*)d_in[4];
    const float* bq   = (const float*)d_in[5];
    const float* wk   = (const float*)d_in[6];
    const float* bk   = (const float*)d_in[7];
    const float* wvw  = (const float*)d_in[8];
    const float* bv   = (const float*)d_in[9];
    const float* wo   = (const float*)d_in[10];
    const float* bo   = (const float*)d_in[11];
    const float* n2g  = (const float*)d_in[12];
    const float* n2b  = (const float*)d_in[13];
    const float* wfc1 = (const float*)d_in[14];
    const float* bfc1 = (const float*)d_in[15];
    const float* wfc2 = (const float*)d_in[16];
    const float* bfc2 = (const float*)d_in[17];
    const float* pw1  = (const float*)d_in[18];
    const float* pb1  = (const float*)d_in[19];
    const float* bng  = (const float*)d_in[20];
    const float* bnb  = (const float*)d_in[21];
    const float* bnm  = (const float*)d_in[22];
    const float* bnv  = (const float*)d_in[23];
    const float* pw2  = (const float*)d_in[24];
    float* out = (float*)d_out;
    u16* ws  = (u16*)d_ws;

    const size_t SZ = (size_t)32768 * 256;  // one [L,C] bf16 slot
    u16* s0   = ws;                // xn -> O -> xn2
    u16* qkv  = ws + SZ;           // packed [L][768] QKV (3 slots)
    u16* wqT  = ws + 4 * SZ;       // q,k,v transposed weights CONTIGUOUS -> fused Wt
    u16* wkT  = wqT + 65536;
    u16* wvT  = wkT + 65536;
    u16* woT  = wvT + 65536;
    u16* fc1T = woT + 65536;
    u16* fc2T = fc1T + 262144;
    u16* biasg = fc2T + 262144;    // 256*8*128*128 bf16 = 67 MB

    transpose_all<<<768, dim3(32, 8), 0, stream>>>(wq, wk, wvw, wo, wfc1, wfc2,
                                                   wqT, wkT, wvT, woT, fc1T, fc2T);
    ln_k<<<8192, 256, 0, stream>>>(x, n1g, n1b, s0);
    // fused QKV projection: [32768,256] x [768,256]^T -> packed [32768,768]
    gemm_bt<<<dim3(6, 256), 256, 0, stream>>>(s0, wqT, bq, bk, bv, nullptr, qkv, nullptr,
                                              32768, 768, 256, 4);
    bias_k<<<256, 256, 0, stream>>>(pos, pw1, pb1, bng, bnb, bnm, bnv, pw2, biasg);
    attn_k<<<dim3(256, 8), 256, 0, stream>>>(qkv, biasg, s0);
    // X1 = x + O@wo + bo -> d_out (fp32)
    gemm_bt<<<dim3(2, 256), 256, 0, stream>>>(s0, woT, bo, nullptr, nullptr, x, nullptr, out,
                                              32768, 256, 256, 2);
    ln_k<<<8192, 256, 0, stream>>>(out, n2g, n2b, s0);
    // fused MLP: out += gelu(xn2@fc1+b1)@fc2+b2, H stays on-chip
    mlp_fused<<<512, 256, 0, stream>>>(s0, fc1T, fc2T, bfc1, bfc2, out);
}

// Round 7
// 320.436 us; speedup vs baseline: 1.3715x; 1.0060x over previous
//
#include <hip/hip_runtime.h>
#include <cstdint>

typedef unsigned short u16;
typedef __bf16 bf16x8 __attribute__((ext_vector_type(8)));
typedef float f32x4 __attribute__((ext_vector_type(4)));

#define LN_EPS 1e-5f
#define SCALE_Q 0.17677669529663689f  // 32^-0.5

__device__ __forceinline__ u16 f2bf(float f) {
    union { float f; unsigned int i; } c; c.f = f;
    unsigned int r = c.i + 0x7FFFu + ((c.i >> 16) & 1u);
    return (u16)(r >> 16);
}
// pack two f32 -> two bf16 (truncation) in one v_perm_b32
__device__ __forceinline__ unsigned pack2(float hi, float lo) {
    return __builtin_amdgcn_perm(__float_as_uint(hi), __float_as_uint(lo), 0x07060302u);
}
// async global->LDS, 16B per lane; lds pointer must be wave-uniform
__device__ __forceinline__ void async16(const void* g, void* l) {
    __builtin_amdgcn_global_load_lds(
        (__attribute__((address_space(1))) unsigned int*)(unsigned long long)g,
        (__attribute__((address_space(3))) unsigned int*)l, 16, 0, 0);
}

// ------------- all 6 weight transposes (+bf16 cast) in one dispatch -------------
__global__ void transpose_all(const float* __restrict__ wq, const float* __restrict__ wk,
                              const float* __restrict__ wv, const float* __restrict__ wo,
                              const float* __restrict__ f1, const float* __restrict__ f2,
                              u16* oq, u16* ok, u16* ov, u16* oo, u16* o1, u16* o2) {
    __shared__ float tile[32][33];
    const int b = blockIdx.x;
    const float* In; u16* Out; int R, C, bx, by;
    if (b < 256) {
        const int m = b >> 6, l = b & 63;
        In = m == 0 ? wq : (m == 1 ? wk : (m == 2 ? wv : wo));
        Out = m == 0 ? oq : (m == 1 ? ok : (m == 2 ? ov : oo));
        R = 256; C = 256; bx = (l & 7) * 32; by = (l >> 3) * 32;
    } else if (b < 512) {
        const int l = b - 256; In = f1; Out = o1; R = 256; C = 1024;
        bx = (l & 31) * 32; by = (l >> 5) * 32;
    } else {
        const int l = b - 512; In = f2; Out = o2; R = 1024; C = 256;
        bx = (l & 7) * 32; by = (l >> 3) * 32;
    }
    const int tx = threadIdx.x, ty = threadIdx.y;
    for (int i = 0; i < 32; i += 8)
        tile[ty + i][tx] = In[(size_t)(by + ty + i) * C + bx + tx];
    __syncthreads();
    for (int i = 0; i < 32; i += 8)
        Out[(size_t)(bx + ty + i) * R + by + tx] = f2bf(tile[tx][ty + i]);
}

// ------------- LayerNorm: one wave per token (C=256); fp32 in -> bf16 out -------------
__global__ __launch_bounds__(256) void ln_k(const float* __restrict__ X, const float* __restrict__ G,
                                            const float* __restrict__ Bt, u16* __restrict__ Y) {
    const int token = blockIdx.x * 4 + (threadIdx.x >> 6);
    const int ln = threadIdx.x & 63;
    const float4 rv = *(const float4*)(X + (size_t)token * 256 + ln * 4);
    float s = rv.x + rv.y + rv.z + rv.w;
    float q = rv.x * rv.x + rv.y * rv.y + rv.z * rv.z + rv.w * rv.w;
    #pragma unroll
    for (int m = 1; m < 64; m <<= 1) { s += __shfl_xor(s, m, 64); q += __shfl_xor(q, m, 64); }
    const float mean = s * (1.f / 256.f);
    const float var  = q * (1.f / 256.f) - mean * mean;
    const float rs   = rsqrtf(var + LN_EPS);
    const float4 gv = *(const float4*)(G + ln * 4);
    const float4 bv = *(const float4*)(Bt + ln * 4);
    ushort4 o;
    o.x = f2bf((rv.x - mean) * rs * gv.x + bv.x);
    o.y = f2bf((rv.y - mean) * rs * gv.y + bv.y);
    o.z = f2bf((rv.z - mean) * rs * gv.z + bv.z);
    o.w = f2bf((rv.w - mean) * rs * gv.w + bv.w);
    *(ushort4*)(Y + (size_t)token * 256 + ln * 4) = o;
}

// ------------- GEMM (B^T form): Y[m,n] = sum_k X[m,k]*Wt[n,k] + epilogue -------------
// mode: 2 = +bias + Res[m,n] (fp32 out) ; 4 = fused-QKV (seg bias, Q scaled, bf16 out)
// sA/sB XOR-swizzled on 16B blocks (mask 7) to break stride-128B bank aliasing.
__global__ __launch_bounds__(256, 2) void gemm_bt(
    const u16* __restrict__ X, const u16* __restrict__ Wt,
    const float* __restrict__ B1, const float* __restrict__ B2, const float* __restrict__ B3,
    const float* __restrict__ Res,
    u16* __restrict__ Ybf, float* __restrict__ Yf,
    int M, int N, int K, int mode) {
    __shared__ alignas(16) u16 sBuf[128 * 128];  // K-loop: sA=sBuf, sB=sBuf+8192; epilogue: C tile
    u16* sA = sBuf;
    u16* sB = sBuf + 128 * 64;
    const int tid = threadIdx.x, wv = tid >> 6, ln = tid & 63;
    const int quad = ln >> 4, l16 = ln & 15;
    const int m0 = blockIdx.y * 128, n0 = blockIdx.x * 128;
    const int mw = (wv >> 1) * 64, nw = (wv & 1) * 64;
    const int r8 = ln >> 3;
    const int kbs = (ln & 7) ^ (r8 & 7);  // swizzled k-block for staging
    const f32x4 z4 = {0.f, 0.f, 0.f, 0.f};
    f32x4 acc[4][4];
    #pragma unroll
    for (int i = 0; i < 4; i++)
        #pragma unroll
        for (int j = 0; j < 4; j++) acc[i][j] = z4;

    for (int k0 = 0; k0 < K; k0 += 64) {
        __syncthreads();
        #pragma unroll
        for (int i = 0; i < 4; i++) {
            const int row = wv * 32 + i * 8;
            async16(X  + (size_t)(m0 + row + r8) * K + k0 + kbs * 8, &sA[row * 64]);
            async16(Wt + (size_t)(n0 + row + r8) * K + k0 + kbs * 8, &sB[row * 64]);
        }
        __syncthreads();
        #pragma unroll
        for (int kk = 0; kk < 2; kk++) {
            bf16x8 af[4], bfr[4];
            #pragma unroll
            for (int i = 0; i < 4; i++) {
                const int ra = mw + i * 16 + l16;
                const int b = kk * 4 + quad;
                af[i] = *(const bf16x8*)&sA[ra * 64 + ((b ^ (ra & 7)) * 8)];
            }
            #pragma unroll
            for (int j = 0; j < 4; j++) {
                const int rb = nw + j * 16 + l16;
                const int b = kk * 4 + quad;
                bfr[j] = *(const bf16x8*)&sB[rb * 64 + ((b ^ (rb & 7)) * 8)];
            }
            #pragma unroll
            for (int i = 0; i < 4; i++)
                #pragma unroll
                for (int j = 0; j < 4; j++)
                    acc[i][j] = __builtin_amdgcn_mfma_f32_16x16x32_bf16(af[i], bfr[j], acc[i][j], 0, 0, 0);
        }
    }
    // epilogue
    const int seg = n0 >> 8;  // for mode 4 (block fully inside one 256-col segment)
    const float* bp = (mode == 4) ? (seg == 0 ? B1 : (seg == 1 ? B2 : B3)) : B1;
    const float sc = (mode == 4 && seg == 0) ? SCALE_Q : 1.f;
    if (mode == 4) {
        __syncthreads();  // done with sA/sB staging reads
        #pragma unroll
        for (int j = 0; j < 4; j++) {
            const int col = nw + j * 16 + l16;
            const float bc = bp[(n0 + col) & 255];
            #pragma unroll
            for (int i = 0; i < 4; i++)
                #pragma unroll
                for (int r = 0; r < 4; r++)
                    sBuf[(mw + i * 16 + quad * 4 + r) * 128 + col] = f2bf((acc[i][j][r] + bc) * sc);
        }
        __syncthreads();
        // coalesced stores: 128 rows x 256B
        #pragma unroll
        for (int it = 0; it < 8; it++) {
            const int idx = it * 256 + tid;
            const int row = idx >> 4, sg = idx & 15;
            *(uint4*)(Ybf + (size_t)(m0 + row) * N + n0 + sg * 8) = *(const uint4*)&sBuf[row * 128 + sg * 8];
        }
    } else {
        #pragma unroll
        for (int j = 0; j < 4; j++) {
            const int col = n0 + nw + j * 16 + l16;
            const float bc = bp[col];
            #pragma unroll
            for (int i = 0; i < 4; i++) {
                #pragma unroll
                for (int r = 0; r < 4; r++) {
                    const int row = m0 + mw + i * 16 + quad * 4 + r;
                    float v = acc[i][j][r] + bc;
                    if (mode == 2) v += Res[(size_t)row * N + col];
                    Yf[(size_t)row * N + col] = v;
                }
            }
        }
    }
}

// ------------- per-window bias: bias[h][t][u] = sum_o pw2[h][o]*relu(ta2[o][t]-ta[o][u]) -------------
__global__ __launch_bounds__(256) void bias_k(
    const float* __restrict__ pos, const float* __restrict__ pw1, const float* __restrict__ pb1,
    const float* __restrict__ bng, const float* __restrict__ bnb, const float* __restrict__ bnm,
    const float* __restrict__ bnv, const float* __restrict__ pw2, u16* __restrict__ Bg) {
    __shared__ float sTa[32 * 128], sTa2[32 * 128];  // o padded 16->32 with zeros
    __shared__ u16 sW[16 * 32];
    __shared__ alignas(16) u16 sOut[4][8 * 128];     // per-wave [h][u] staging for one t
    const int n = blockIdx.x, wh = n >> 4, ww = n & 15;
    const int tid = threadIdx.x, wv = tid >> 6, ln = tid & 63;
    const int quad = ln >> 4, l16 = ln & 15;
    for (int r = 0; r < 16; r++) {
        const int e = tid + r * 256, o = e >> 7, t = e & 127;
        float ta = 0.f, ta2 = 0.f;
        if (o < 16) {
            const int l = (wh * 4 + (t >> 5)) * 512 + ww * 32 + (t & 31);
            const float sv = rsqrtf(bnv[o] + LN_EPS) * bng[o];
            ta = sv * (pw1[o * 2] * pos[l * 2] + pw1[o * 2 + 1] * pos[l * 2 + 1]);
            ta2 = ta + (pb1[o] - bnm[o]) * sv + bnb[o];
        }
        sTa[o * 128 + t] = ta; sTa2[o * 128 + t] = ta2;
    }
    for (int r = 0; r < 2; r++) {
        const int e = tid + r * 256, h = e >> 5, o = e & 31;
        sW[e] = (h < 8 && o < 16) ? f2bf(pw2[h * 16 + o]) : (u16)0;
    }
    __syncthreads();
    const bf16x8 af = *(const bf16x8*)&sW[l16 * 32 + quad * 8];
    float uo[8][8];
    #pragma unroll
    for (int c = 0; c < 8; c++)
        #pragma unroll
        for (int j = 0; j < 8; j++)
            uo[c][j] = sTa[(quad * 8 + j) * 128 + c * 16 + l16];
    const f32x4 z4 = {0.f, 0.f, 0.f, 0.f};
    u16* outb = Bg + (size_t)n * 131072;  // 8*128*128
    for (int tl = 0; tl < 32; tl++) {
        const int t = wv * 32 + tl;
        float t2[8];
        #pragma unroll
        for (int j = 0; j < 8; j++) t2[j] = sTa2[(quad * 8 + j) * 128 + t];
        #pragma unroll
        for (int c = 0; c < 8; c++) {
            float rl[8];
            #pragma unroll
            for (int j = 0; j < 8; j++) rl[j] = fmaxf(t2[j] - uo[c][j], 0.f);
            union { unsigned u[4]; bf16x8 v; } bb;
            #pragma unroll
            for (int p = 0; p < 4; p++) bb.u[p] = pack2(rl[2 * p + 1], rl[2 * p]);
            const f32x4 cc = __builtin_amdgcn_mfma_f32_16x16x32_bf16(af, bb.v, z4, 0, 0, 0);
            if (quad < 2) {
                #pragma unroll
                for (int r = 0; r < 4; r++)
                    sOut[wv][(quad * 4 + r) * 128 + c * 16 + l16] =
                        (u16)(__float_as_uint(cc[r]) >> 16);
            }
        }
        // coalesced flush: 8 h-rows x 256B (wave-local, ds ordering within wave)
        #pragma unroll
        for (int it = 0; it < 2; it++) {
            const int idx = it * 64 + ln;
            const int h = idx >> 4, u8 = idx & 15;
            *(uint4*)(outb + (size_t)h * 16384 + t * 128 + u8 * 8) = *(const uint4*)&sOut[wv][idx * 8];
        }
    }
}

// ------------- windowed attention, one block per (window, head) -------------
// sQ/sK swizzled (mask 3), sVt swizzled (mask 15) to break power-of-2 row-stride aliasing.
__global__ __launch_bounds__(256, 2) void attn_k(
    const u16* __restrict__ Qkv, const u16* __restrict__ Bg, u16* __restrict__ Ob) {
    constexpr int SPS = 136;
    __shared__ alignas(16) u16 sQ[128 * 32];
    __shared__ alignas(16) u16 sK[128 * 32];
    __shared__ alignas(16) u16 sVt[32 * 128];
    __shared__ alignas(16) u16 sPB[128 * SPS];  // bias tile (stride 128), then P (stride 136)

    const int n = blockIdx.x, h = blockIdx.y;
    const int tid = threadIdx.x, wv = tid >> 6, ln = tid & 63;
    const int quad = ln >> 4, l16 = ln & 15;
    const int wh = n >> 4, ww = n & 15;

    {
        const int rw = ln >> 2;                 // row-within-1KB-chunk for Q/K staging
        const int tb = wv * 16 + rw;
        const int kbq = (ln & 3) ^ (rw & 3);    // swizzled d-block
        #pragma unroll
        for (int i = 0; i < 2; i++) {
            const int tt = tb + i * 64;
            const int l = (wh * 4 + (tt >> 5)) * 512 + ww * 32 + (tt & 31);
            const size_t g = (size_t)l * 768 + h * 32 + kbq * 8;
            async16(Qkv + g, &sQ[(wv * 16 + i * 64) * 32]);
            async16(Qkv + g + 256, &sK[(wv * 16 + i * 64) * 32]);
        }
        const u16* bsrc = Bg + (size_t)(n * 8 + h) * 16384;
        #pragma unroll
        for (int rr = 0; rr < 8; rr++)
            async16(bsrc + rr * 2048 + wv * 512 + ln * 8, &sPB[rr * 2048 + wv * 512]);
        const int d8 = ln & 3;
        #pragma unroll
        for (int i = 0; i < 2; i++) {
            const int tt = tb + i * 64;
            const int l = (wh * 4 + (tt >> 5)) * 512 + ww * 32 + (tt & 31);
            const uint4 raw = *(const uint4*)(Qkv + (size_t)l * 768 + 512 + h * 32 + d8 * 8);
            const u16* e = (const u16*)&raw;
            #pragma unroll
            for (int j = 0; j < 8; j++) {
                const int row = d8 * 8 + j;  // d index
                sVt[row * 128 + (((tt >> 3) ^ (row & 15)) * 8) + (tt & 7)] = e[j];
            }
        }
    }
    __syncthreads();

    const f32x4 z4 = {0.f, 0.f, 0.f, 0.f};
    f32x4 acc[2][8];
    {
        bf16x8 qf[2], kf[8];
        #pragma unroll
        for (int i = 0; i < 2; i++) {
            const int t = wv * 32 + i * 16 + l16;
            qf[i] = *(const bf16x8*)&sQ[t * 32 + ((quad ^ (t & 3)) * 8)];
        }
        #pragma unroll
        for (int j = 0; j < 8; j++) {
            const int t = j * 16 + l16;
            kf[j] = *(const bf16x8*)&sK[t * 32 + ((quad ^ (t & 3)) * 8)];
        }
        #pragma unroll
        for (int i = 0; i < 2; i++)
            #pragma unroll
            for (int j = 0; j < 8; j++)
                acc[i][j] = __builtin_amdgcn_mfma_f32_16x16x32_bf16(qf[i], kf[j], z4, 0, 0, 0);
    }
    #pragma unroll
    for (int i = 0; i < 2; i++)
        #pragma unroll
        for (int j = 0; j < 8; j++)
            #pragma unroll
            for (int r = 0; r < 4; r++) {
                const int t = wv * 32 + i * 16 + quad * 4 + r;
                const unsigned bu = sPB[t * 128 + j * 16 + l16];
                acc[i][j][r] += __uint_as_float(bu << 16);
            }
    float rinv[2][4];
    #pragma unroll
    for (int i = 0; i < 2; i++) {
        #pragma unroll
        for (int r = 0; r < 4; r++) {
            float mx = acc[i][0][r];
            #pragma unroll
            for (int j = 1; j < 8; j++) mx = fmaxf(mx, acc[i][j][r]);
            #pragma unroll
            for (int m = 1; m < 16; m <<= 1) mx = fmaxf(mx, __shfl_xor(mx, m, 64));
            float sm = 0.f;
            #pragma unroll
            for (int j = 0; j < 8; j++) {
                const float p = __expf(acc[i][j][r] - mx);
                acc[i][j][r] = p;
                sm += p;
            }
            #pragma unroll
            for (int m = 1; m < 16; m <<= 1) sm += __shfl_xor(sm, m, 64);
            rinv[i][r] = 1.f / sm;
        }
    }
    __syncthreads();
    #pragma unroll
    for (int i = 0; i < 2; i++)
        #pragma unroll
        for (int j = 0; j < 8; j++)
            #pragma unroll
            for (int r = 0; r < 4; r++) {
                const int t = wv * 32 + i * 16 + quad * 4 + r;
                sPB[t * SPS + j * 16 + l16] = (u16)(__float_as_uint(acc[i][j][r]) >> 16);
            }
    __syncthreads();
    f32x4 oacc[2][2];
    #pragma unroll
    for (int i = 0; i < 2; i++)
        #pragma unroll
        for (int jd = 0; jd < 2; jd++) oacc[i][jd] = z4;
    #pragma unroll
    for (int ku = 0; ku < 4; ku++) {
        bf16x8 pf[2], vf[2];
        #pragma unroll
        for (int i = 0; i < 2; i++) pf[i] = *(const bf16x8*)&sPB[(wv * 32 + i * 16 + l16) * SPS + ku * 32 + quad * 8];
        #pragma unroll
        for (int jd = 0; jd < 2; jd++) {
            const int rv = jd * 16 + l16;
            const int b = ku * 4 + quad;
            vf[jd] = *(const bf16x8*)&sVt[rv * 128 + ((b ^ (rv & 15)) * 8)];
        }
        #pragma unroll
        for (int i = 0; i < 2; i++)
            #pragma unroll
            for (int jd = 0; jd < 2; jd++)
                oacc[i][jd] = __builtin_amdgcn_mfma_f32_16x16x32_bf16(pf[i], vf[jd], oacc[i][jd], 0, 0, 0);
    }
    #pragma unroll
    for (int i = 0; i < 2; i++)
        #pragma unroll
        for (int jd = 0; jd < 2; jd++)
            #pragma unroll
            for (int r = 0; r < 4; r++) {
                const int t = wv * 32 + i * 16 + quad * 4 + r;
                const int d = jd * 16 + l16;
                const int l = (wh * 4 + (t >> 5)) * 512 + ww * 32 + (t & 31);
                Ob[(size_t)l * 256 + h * 32 + d] = f2bf(oacc[i][jd][r] * rinv[i][r]);
            }
}

// ------------- fused MLP: out[m] += gelu(xn2[m]@fc1 + b1)@fc2 + b2  (H never hits HBM) -------------
// Software-pipelined: weights staged in 16KB chunks, double-buffered (sW0/sW1); the NEXT chunk's
// global_load_lds is issued BEFORE computing the current chunk, so the end-of-step barrier drains
// loads that flew during ~16 MFMA + ds_reads. All tiles XOR-swizzled on 16B blocks.
// LDS: sA 32KB + sW0 16KB + sW1 16KB + sH 16KB = 80KB -> 2 blocks/CU.
__global__ __launch_bounds__(256, 2) void mlp_fused(
    const u16* __restrict__ Xn, const u16* __restrict__ fc1T, const u16* __restrict__ fc2T,
    const float* __restrict__ b1, const float* __restrict__ b2, float* __restrict__ Out) {
    __shared__ alignas(16) u16 sA[64 * 256];   // row 512B, swizzle mask 7
    __shared__ alignas(16) u16 sW0[64 * 128];  // 16KB chunk buffer (fc1: 128r x 64k | fc2: 256r x 32k)
    __shared__ alignas(16) u16 sW1[64 * 128];
    __shared__ alignas(16) u16 sH[64 * 128];   // row 256B, swizzle mask 15
    const int tid = threadIdx.x, wv = tid >> 6, ln = tid & 63;
    const int quad = ln >> 4, l16 = ln & 15;
    const int m0 = blockIdx.x * 64;
    const int mw = (wv >> 1) * 32;         // 2-way M split
    const int nw1 = (wv & 1) * 64;         // fc1 N split (128 cols)
    const int nw2 = (wv & 1) * 128;        // fc2 N split (256 cols)

    // chunk staging: fc1 chunk (c,kc) = rows [c*128,+128) x k [kc*64,+64), row 128B, mask 7
    auto stage_f1 = [&](int c, int kc, u16* buf) {
        #pragma unroll
        for (int rr = 0; rr < 4; rr++) {
            const int r0 = (rr * 4 + wv) * 8;
            const int row = r0 + (ln >> 3);
            const int kb = (ln & 7) ^ (row & 7);
            async16(fc1T + (size_t)(c * 128 + row) * 256 + kc * 64 + kb * 8, &buf[r0 * 64]);
        }
    };
    // fc2 chunk (c,kc) = rows [0,256) x k [c*128+kc*32,+32), row 64B, mask 3
    auto stage_f2 = [&](int c, int kc, u16* buf) {
        #pragma unroll
        for (int rr = 0; rr < 4; rr++) {
            const int r0 = (rr * 4 + wv) * 16;
            const int row = r0 + (ln >> 2);
            const int kb = (ln & 3) ^ (row & 3);
            async16(fc2T + (size_t)row * 1024 + c * 128 + kc * 32 + kb * 8, &buf[r0 * 32]);
        }
    };

    // stage A once (swizzled): each async16 covers 2 rows
    #pragma unroll
    for (int rr = 0; rr < 8; rr++) {
        const int row2 = rr * 8 + wv * 2;
        const int row = row2 + (ln >> 5);
        const int kb = (ln & 31) ^ (row & 7);
        async16(Xn + (size_t)(m0 + row) * 256 + kb * 8, &sA[row2 * 256]);
    }
    stage_f1(0, 0, sW0);

    const f32x4 z4 = {0.f, 0.f, 0.f, 0.f};
    f32x4 acc2[2][8];
    #pragma unroll
    for (int i = 0; i < 2; i++)
        #pragma unroll
        for (int j = 0; j < 8; j++) acc2[i][j] = z4;

    __syncthreads();  // sA + first chunk ready
    for (int c = 0; c < 8; c++) {
        // ---- fc1 phase: 4 chunks of k=64 ----
        f32x4 acc1[2][4];
        #pragma unroll
        for (int i = 0; i < 2; i++)
            #pragma unroll
            for (int j = 0; j < 4; j++) acc1[i][j] = z4;
        #pragma unroll
        for (int kc = 0; kc < 4; kc++) {
            u16* cur = (kc & 1) ? sW1 : sW0;
            u16* nxt = (kc & 1) ? sW0 : sW1;
            if (kc < 3) stage_f1(c, kc + 1, nxt);  // prefetch flies during compute
            #pragma unroll
            for (int kk = 0; kk < 2; kk++) {
                bf16x8 af[2], bfr[4];
                #pragma unroll
                for (int i = 0; i < 2; i++) {
                    const int ra = mw + i * 16 + l16;
                    const int b = kc * 8 + kk * 4 + quad;
                    af[i] = *(const bf16x8*)&sA[ra * 256 + ((b ^ (ra & 7)) * 8)];
                }
                #pragma unroll
                for (int j = 0; j < 4; j++) {
                    const int rb = nw1 + j * 16 + l16;
                    const int b = kk * 4 + quad;
                    bfr[j] = *(const bf16x8*)&cur[rb * 64 + ((b ^ (rb & 7)) * 8)];
                }
                #pragma unroll
                for (int i = 0; i < 2; i++)
                    #pragma unroll
                    for (int j = 0; j < 4; j++)
                        acc1[i][j] = __builtin_amdgcn_mfma_f32_16x16x32_bf16(af[i], bfr[j], acc1[i][j], 0, 0, 0);
            }
            __syncthreads();  // drains prefetch (overlapped) + protects cur reuse
        }
        // ---- gelu slot: prefetch fc2 chunk0 (sW0), write sH ----
        stage_f2(c, 0, sW0);
        #pragma unroll
        for (int j = 0; j < 4; j++) {
            const float bc = b1[c * 128 + nw1 + j * 16 + l16];
            const int col = nw1 + j * 16 + l16;
            const int blk = col >> 3, off = col & 7;
            #pragma unroll
            for (int i = 0; i < 2; i++)
                #pragma unroll
                for (int r = 0; r < 4; r++) {
                    float v = acc1[i][j][r] + bc;
                    const float p = v * v;
                    const float qq = fmaf(p, -0.07135481283f, -1.5957691216f);
                    v = v / (1.f + __expf(v * qq));  // gelu approx
                    const int row = mw + i * 16 + quad * 4 + r;
                    sH[row * 128 + ((blk ^ (row & 15)) * 8) + off] = f2bf(v);
                }
        }
        __syncthreads();  // sH visible + fc2 chunk0 ready
        // ---- fc2 phase: 4 chunks of k=32 ----
        #pragma unroll
        for (int kc = 0; kc < 4; kc++) {
            u16* cur = (kc & 1) ? sW1 : sW0;
            u16* nxt = (kc & 1) ? sW0 : sW1;
            if (kc < 3) stage_f2(c, kc + 1, nxt);
            else if (c < 7) stage_f1(c + 1, 0, nxt);  // nxt == sW0, matches next c's fc1 kc0
            bf16x8 pf[2], bfr[8];
            #pragma unroll
            for (int i = 0; i < 2; i++) {
                const int rp = mw + i * 16 + l16;
                const int b = kc * 4 + quad;
                pf[i] = *(const bf16x8*)&sH[rp * 128 + ((b ^ (rp & 15)) * 8)];
            }
            #pragma unroll
            for (int j = 0; j < 8; j++) {
                const int rb = nw2 + j * 16 + l16;
                bfr[j] = *(const bf16x8*)&cur[rb * 32 + ((quad ^ (rb & 3)) * 8)];
            }
            #pragma unroll
            for (int i = 0; i < 2; i++)
                #pragma unroll
                for (int j = 0; j < 8; j++)
                    acc2[i][j] = __builtin_amdgcn_mfma_f32_16x16x32_bf16(pf[i], bfr[j], acc2[i][j], 0, 0, 0);
            __syncthreads();
        }
    }
    // epilogue: out = acc2 + b2 + out (residual, in-place)
    #pragma unroll
    for (int j = 0; j < 8; j++) {
        const int col = nw2 + j * 16 + l16;
        const float bc = b2[col];
        #pragma unroll
        for (int i = 0; i < 2; i++)
            #pragma unroll
            for (int r = 0; r < 4; r++) {
                const size_t idx = (size_t)(m0 + mw + i * 16 + quad * 4 + r) * 256 + col;
                Out[idx] = acc2[i][j][r] + bc + Out[idx];
            }
    }
}

extern "C" void kernel_launch(void* const* d_in, const int* in_sizes, int n_in,
                              void* d_out, int out_size, void* d_ws, size_t ws_size,
                              hipStream_t stream) {
    const float* x    = (const float*)d_in[0];
    const float* pos  = (const float*)d_in[1];
    const float* n1g  = (const float*)d_in[2];
    const float* n1b  = (const float*)d_in[3];
    const float* wq   = (const float*)d_in[4];
    const float* bq   = (const float*)d_in[5];
    const float* wk   = (const float*)d_in[6];
    const float* bk   = (const float*)d_in[7];
    const float* wvw  = (const float*)d_in[8];
    const float* bv   = (const float*)d_in[9];
    const float* wo   = (const float*)d_in[10];
    const float* bo   = (const float*)d_in[11];
    const float* n2g  = (const float*)d_in[12];
    const float* n2b  = (const float*)d_in[13];
    const float* wfc1 = (const float*)d_in[14];
    const float* bfc1 = (const float*)d_in[15];
    const float* wfc2 = (const float*)d_in[16];
    const float* bfc2 = (const float*)d_in[17];
    const float* pw1  = (const float*)d_in[18];
    const float* pb1  = (const float*)d_in[19];
    const float* bng  = (const float*)d_in[20];
    const float* bnb  = (const float*)d_in[21];
    const float* bnm  = (const float*)d_in[22];
    const float* bnv  = (const float*)d_in[23];
    const float* pw2  = (const float*)d_in[24];
    float* out = (float*)d_out;
    u16* ws  = (u16*)d_ws;

    const size_t SZ = (size_t)32768 * 256;  // one [L,C] bf16 slot
    u16* s0   = ws;                // xn -> O -> xn2
    u16* qkv  = ws + SZ;           // packed [L][768] QKV (3 slots)
    u16* wqT  = ws + 4 * SZ;       // q,k,v transposed weights CONTIGUOUS -> fused Wt
    u16* wkT  = wqT + 65536;
    u16* wvT  = wkT + 65536;
    u16* woT  = wvT + 65536;
    u16* fc1T = woT + 65536;
    u16* fc2T = fc1T + 262144;
    u16* biasg = fc2T + 262144;    // 256*8*128*128 bf16 = 67 MB

    transpose_all<<<768, dim3(32, 8), 0, stream>>>(wq, wk, wvw, wo, wfc1, wfc2,
                                                   wqT, wkT, wvT, woT, fc1T, fc2T);
    ln_k<<<8192, 256, 0, stream>>>(x, n1g, n1b, s0);
    // fused QKV projection: [32768,256] x [768,256]^T -> packed [32768,768]
    gemm_bt<<<dim3(6, 256), 256, 0, stream>>>(s0, wqT, bq, bk, bv, nullptr, qkv, nullptr,
                                              32768, 768, 256, 4);
    bias_k<<<256, 256, 0, stream>>>(pos, pw1, pb1, bng, bnb, bnm, bnv, pw2, biasg);
    attn_k<<<dim3(256, 8), 256, 0, stream>>>(qkv, biasg, s0);
    // X1 = x + O@wo + bo -> d_out (fp32)
    gemm_bt<<<dim3(2, 256), 256, 0, stream>>>(s0, woT, bo, nullptr, nullptr, x, nullptr, out,
                                              32768, 256, 256, 2);
    ln_k<<<8192, 256, 0, stream>>>(out, n2g, n2b, s0);
    // fused MLP: out += gelu(xn2@fc1+b1)@fc2+b2, H stays on-chip
    mlp_fused<<<512, 256, 0, stream>>>(s0, fc1T, fc2T, bfc1, bfc2, out);
}

// Round 8
// 297.356 us; speedup vs baseline: 1.4780x; 1.0776x over previous
//
#include <hip/hip_runtime.h>
#include <cstdint>

typedef unsigned short u16;
typedef __bf16 bf16x8 __attribute__((ext_vector_type(8)));
typedef float f32x4 __attribute__((ext_vector_type(4)));

#define LN_EPS 1e-5f
#define SCALE_Q 0.17677669529663689f  // 32^-0.5

__device__ __forceinline__ u16 f2bf(float f) {
    union { float f; unsigned int i; } c; c.f = f;
    unsigned int r = c.i + 0x7FFFu + ((c.i >> 16) & 1u);
    return (u16)(r >> 16);
}
// pack two f32 -> two bf16 (truncation) in one v_perm_b32
__device__ __forceinline__ unsigned pack2(float hi, float lo) {
    return __builtin_amdgcn_perm(__float_as_uint(hi), __float_as_uint(lo), 0x07060302u);
}
// async global->LDS, 16B per lane; lds pointer must be wave-uniform
__device__ __forceinline__ void async16(const void* g, void* l) {
    __builtin_amdgcn_global_load_lds(
        (__attribute__((address_space(1))) unsigned int*)(unsigned long long)g,
        (__attribute__((address_space(3))) unsigned int*)l, 16, 0, 0);
}

// ------------- prep: 6 weight transposes (+bf16 cast) AND LayerNorm1, one dispatch -------------
__global__ __launch_bounds__(256) void prep_k(
    const float* __restrict__ wq, const float* __restrict__ wk,
    const float* __restrict__ wv, const float* __restrict__ wo,
    const float* __restrict__ f1, const float* __restrict__ f2,
    u16* oq, u16* ok, u16* ov, u16* oo, u16* o1, u16* o2,
    const float* __restrict__ X, const float* __restrict__ G,
    const float* __restrict__ Bt, u16* __restrict__ Y) {
    __shared__ float tile[32][33];
    const int b = blockIdx.x;
    const int tid = threadIdx.x;
    if (b < 768) {
        const float* In; u16* Out; int R, C, bx, by;
        if (b < 256) {
            const int m = b >> 6, l = b & 63;
            In = m == 0 ? wq : (m == 1 ? wk : (m == 2 ? wv : wo));
            Out = m == 0 ? oq : (m == 1 ? ok : (m == 2 ? ov : oo));
            R = 256; C = 256; bx = (l & 7) * 32; by = (l >> 3) * 32;
        } else if (b < 512) {
            const int l = b - 256; In = f1; Out = o1; R = 256; C = 1024;
            bx = (l & 31) * 32; by = (l >> 5) * 32;
        } else {
            const int l = b - 512; In = f2; Out = o2; R = 1024; C = 256;
            bx = (l & 7) * 32; by = (l >> 3) * 32;
        }
        const int tx = tid & 31, ty = tid >> 5;
        for (int i = 0; i < 32; i += 8)
            tile[ty + i][tx] = In[(size_t)(by + ty + i) * C + bx + tx];
        __syncthreads();
        for (int i = 0; i < 32; i += 8)
            Out[(size_t)(bx + ty + i) * R + by + tx] = f2bf(tile[tx][ty + i]);
    } else {
        const int token = (b - 768) * 4 + (tid >> 6);
        const int ln = tid & 63;
        const float4 rv = *(const float4*)(X + (size_t)token * 256 + ln * 4);
        float s = rv.x + rv.y + rv.z + rv.w;
        float q = rv.x * rv.x + rv.y * rv.y + rv.z * rv.z + rv.w * rv.w;
        #pragma unroll
        for (int m = 1; m < 64; m <<= 1) { s += __shfl_xor(s, m, 64); q += __shfl_xor(q, m, 64); }
        const float mean = s * (1.f / 256.f);
        const float var  = q * (1.f / 256.f) - mean * mean;
        const float rs   = rsqrtf(var + LN_EPS);
        const float4 gv = *(const float4*)(G + ln * 4);
        const float4 bv = *(const float4*)(Bt + ln * 4);
        ushort4 o;
        o.x = f2bf((rv.x - mean) * rs * gv.x + bv.x);
        o.y = f2bf((rv.y - mean) * rs * gv.y + bv.y);
        o.z = f2bf((rv.z - mean) * rs * gv.z + bv.z);
        o.w = f2bf((rv.w - mean) * rs * gv.w + bv.w);
        *(ushort4*)(Y + (size_t)token * 256 + ln * 4) = o;
    }
}

// ------------- fused dispatch: QKV GEMM (blocks 0..1535) + window bias (blocks 1536..1791) -------------
// GEMM: qkv[m, 0..767] = xn @ [wq|wk|wv]^T + seg bias, Q scaled; bf16 out via LDS-coalesced stores.
// Bias: bias[n][h][t][u] = sum_o pw2[h][o]*relu(ta2[o][t]-ta[o][u]) via MFMA over o.
__global__ __launch_bounds__(256, 2) void qkvbias_k(
    const u16* __restrict__ X, const u16* __restrict__ Wt,
    const float* __restrict__ B1, const float* __restrict__ B2, const float* __restrict__ B3,
    u16* __restrict__ Ybf,
    const float* __restrict__ pos, const float* __restrict__ pw1, const float* __restrict__ pb1,
    const float* __restrict__ bng, const float* __restrict__ bnb, const float* __restrict__ bnm,
    const float* __restrict__ bnv, const float* __restrict__ pw2, u16* __restrict__ Bg) {
    __shared__ alignas(16) unsigned char raw[42 * 1024];
    const int tid = threadIdx.x, wv = tid >> 6, ln = tid & 63;
    const int quad = ln >> 4, l16 = ln & 15;
    const f32x4 z4 = {0.f, 0.f, 0.f, 0.f};
    if (blockIdx.x < 1536) {
        // ================= QKV GEMM =================
        u16* sBuf = (u16*)raw;
        u16* sA = sBuf;
        u16* sB = sBuf + 128 * 64;
        const int n0 = (blockIdx.x % 6) * 128, m0 = (blockIdx.x / 6) * 128;
        const int K = 256, N = 768;
        const int mw = (wv >> 1) * 64, nw = (wv & 1) * 64;
        const int r8 = ln >> 3;
        const int kbs = (ln & 7) ^ (r8 & 7);
        f32x4 acc[4][4];
        #pragma unroll
        for (int i = 0; i < 4; i++)
            #pragma unroll
            for (int j = 0; j < 4; j++) acc[i][j] = z4;
        for (int k0 = 0; k0 < K; k0 += 64) {
            __syncthreads();
            #pragma unroll
            for (int i = 0; i < 4; i++) {
                const int row = wv * 32 + i * 8;
                async16(X  + (size_t)(m0 + row + r8) * K + k0 + kbs * 8, &sA[row * 64]);
                async16(Wt + (size_t)(n0 + row + r8) * K + k0 + kbs * 8, &sB[row * 64]);
            }
            __syncthreads();
            #pragma unroll
            for (int kk = 0; kk < 2; kk++) {
                bf16x8 af[4], bfr[4];
                #pragma unroll
                for (int i = 0; i < 4; i++) {
                    const int ra = mw + i * 16 + l16;
                    const int bb = kk * 4 + quad;
                    af[i] = *(const bf16x8*)&sA[ra * 64 + ((bb ^ (ra & 7)) * 8)];
                }
                #pragma unroll
                for (int j = 0; j < 4; j++) {
                    const int rb = nw + j * 16 + l16;
                    const int bb = kk * 4 + quad;
                    bfr[j] = *(const bf16x8*)&sB[rb * 64 + ((bb ^ (rb & 7)) * 8)];
                }
                #pragma unroll
                for (int i = 0; i < 4; i++)
                    #pragma unroll
                    for (int j = 0; j < 4; j++)
                        acc[i][j] = __builtin_amdgcn_mfma_f32_16x16x32_bf16(af[i], bfr[j], acc[i][j], 0, 0, 0);
            }
        }
        const int seg = n0 >> 8;
        const float* bp = seg == 0 ? B1 : (seg == 1 ? B2 : B3);
        const float sc = seg == 0 ? SCALE_Q : 1.f;
        __syncthreads();
        #pragma unroll
        for (int j = 0; j < 4; j++) {
            const int col = nw + j * 16 + l16;
            const float bc = bp[(n0 + col) & 255];
            #pragma unroll
            for (int i = 0; i < 4; i++)
                #pragma unroll
                for (int r = 0; r < 4; r++)
                    sBuf[(mw + i * 16 + quad * 4 + r) * 128 + col] = f2bf((acc[i][j][r] + bc) * sc);
        }
        __syncthreads();
        #pragma unroll
        for (int it = 0; it < 8; it++) {
            const int idx = it * 256 + tid;
            const int row = idx >> 4, sg = idx & 15;
            *(uint4*)(Ybf + (size_t)(m0 + row) * N + n0 + sg * 8) = *(const uint4*)&sBuf[row * 128 + sg * 8];
        }
    } else {
        // ================= window bias =================
        float* sTa  = (float*)raw;               // 16KB
        float* sTa2 = sTa + 32 * 128;            // 16KB
        u16*   sW   = (u16*)(sTa2 + 32 * 128);   // 1KB
        u16*   sOut = sW + 512;                  // 8KB (4 waves x 8*128)
        const int n = blockIdx.x - 1536, wh = n >> 4, ww = n & 15;
        for (int r = 0; r < 16; r++) {
            const int e = tid + r * 256, o = e >> 7, t = e & 127;
            float ta = 0.f, ta2 = 0.f;
            if (o < 16) {
                const int l = (wh * 4 + (t >> 5)) * 512 + ww * 32 + (t & 31);
                const float sv = rsqrtf(bnv[o] + LN_EPS) * bng[o];
                ta = sv * (pw1[o * 2] * pos[l * 2] + pw1[o * 2 + 1] * pos[l * 2 + 1]);
                ta2 = ta + (pb1[o] - bnm[o]) * sv + bnb[o];
            }
            sTa[o * 128 + t] = ta; sTa2[o * 128 + t] = ta2;
        }
        for (int r = 0; r < 2; r++) {
            const int e = tid + r * 256, h = e >> 5, o = e & 31;
            sW[e] = (h < 8 && o < 16) ? f2bf(pw2[h * 16 + o]) : (u16)0;
        }
        __syncthreads();
        const bf16x8 af = *(const bf16x8*)&sW[l16 * 32 + quad * 8];
        float uo[8][8];
        #pragma unroll
        for (int c = 0; c < 8; c++)
            #pragma unroll
            for (int j = 0; j < 8; j++)
                uo[c][j] = sTa[(quad * 8 + j) * 128 + c * 16 + l16];
        u16* outb = Bg + (size_t)n * 131072;
        for (int tl = 0; tl < 32; tl++) {
            const int t = wv * 32 + tl;
            float t2[8];
            #pragma unroll
            for (int j = 0; j < 8; j++) t2[j] = sTa2[(quad * 8 + j) * 128 + t];
            #pragma unroll
            for (int c = 0; c < 8; c++) {
                float rl[8];
                #pragma unroll
                for (int j = 0; j < 8; j++) rl[j] = fmaxf(t2[j] - uo[c][j], 0.f);
                union { unsigned u[4]; bf16x8 v; } bb;
                #pragma unroll
                for (int p = 0; p < 4; p++) bb.u[p] = pack2(rl[2 * p + 1], rl[2 * p]);
                const f32x4 cc = __builtin_amdgcn_mfma_f32_16x16x32_bf16(af, bb.v, z4, 0, 0, 0);
                if (quad < 2) {
                    #pragma unroll
                    for (int r = 0; r < 4; r++)
                        sOut[wv * 1024 + (quad * 4 + r) * 128 + c * 16 + l16] =
                            (u16)(__float_as_uint(cc[r]) >> 16);
                }
            }
            #pragma unroll
            for (int it = 0; it < 2; it++) {
                const int idx = it * 64 + ln;
                const int h = idx >> 4, u8 = idx & 15;
                *(uint4*)(outb + (size_t)h * 16384 + t * 128 + u8 * 8) = *(const uint4*)&sOut[wv * 1024 + idx * 8];
            }
        }
    }
}

// ------------- windowed attention, one block per (window, head) -------------
// sQ/sK swizzled (mask 3), sVt swizzled (mask 15) to break power-of-2 row-stride aliasing.
__global__ __launch_bounds__(256, 2) void attn_k(
    const u16* __restrict__ Qkv, const u16* __restrict__ Bg, u16* __restrict__ Ob) {
    constexpr int SPS = 136;
    __shared__ alignas(16) u16 sQ[128 * 32];
    __shared__ alignas(16) u16 sK[128 * 32];
    __shared__ alignas(16) u16 sVt[32 * 128];
    __shared__ alignas(16) u16 sPB[128 * SPS];  // bias tile (stride 128), then P (stride 136)

    const int n = blockIdx.x, h = blockIdx.y;
    const int tid = threadIdx.x, wv = tid >> 6, ln = tid & 63;
    const int quad = ln >> 4, l16 = ln & 15;
    const int wh = n >> 4, ww = n & 15;

    {
        const int rw = ln >> 2;
        const int tb = wv * 16 + rw;
        const int kbq = (ln & 3) ^ (rw & 3);
        #pragma unroll
        for (int i = 0; i < 2; i++) {
            const int tt = tb + i * 64;
            const int l = (wh * 4 + (tt >> 5)) * 512 + ww * 32 + (tt & 31);
            const size_t g = (size_t)l * 768 + h * 32 + kbq * 8;
            async16(Qkv + g, &sQ[(wv * 16 + i * 64) * 32]);
            async16(Qkv + g + 256, &sK[(wv * 16 + i * 64) * 32]);
        }
        const u16* bsrc = Bg + (size_t)(n * 8 + h) * 16384;
        #pragma unroll
        for (int rr = 0; rr < 8; rr++)
            async16(bsrc + rr * 2048 + wv * 512 + ln * 8, &sPB[rr * 2048 + wv * 512]);
        const int d8 = ln & 3;
        #pragma unroll
        for (int i = 0; i < 2; i++) {
            const int tt = tb + i * 64;
            const int l = (wh * 4 + (tt >> 5)) * 512 + ww * 32 + (tt & 31);
            const uint4 rawv = *(const uint4*)(Qkv + (size_t)l * 768 + 512 + h * 32 + d8 * 8);
            const u16* e = (const u16*)&rawv;
            #pragma unroll
            for (int j = 0; j < 8; j++) {
                const int row = d8 * 8 + j;
                sVt[row * 128 + (((tt >> 3) ^ (row & 15)) * 8) + (tt & 7)] = e[j];
            }
        }
    }
    __syncthreads();

    const f32x4 z4 = {0.f, 0.f, 0.f, 0.f};
    f32x4 acc[2][8];
    {
        bf16x8 qf[2], kf[8];
        #pragma unroll
        for (int i = 0; i < 2; i++) {
            const int t = wv * 32 + i * 16 + l16;
            qf[i] = *(const bf16x8*)&sQ[t * 32 + ((quad ^ (t & 3)) * 8)];
        }
        #pragma unroll
        for (int j = 0; j < 8; j++) {
            const int t = j * 16 + l16;
            kf[j] = *(const bf16x8*)&sK[t * 32 + ((quad ^ (t & 3)) * 8)];
        }
        #pragma unroll
        for (int i = 0; i < 2; i++)
            #pragma unroll
            for (int j = 0; j < 8; j++)
                acc[i][j] = __builtin_amdgcn_mfma_f32_16x16x32_bf16(qf[i], kf[j], z4, 0, 0, 0);
    }
    #pragma unroll
    for (int i = 0; i < 2; i++)
        #pragma unroll
        for (int j = 0; j < 8; j++)
            #pragma unroll
            for (int r = 0; r < 4; r++) {
                const int t = wv * 32 + i * 16 + quad * 4 + r;
                const unsigned bu = sPB[t * 128 + j * 16 + l16];
                acc[i][j][r] += __uint_as_float(bu << 16);
            }
    float rinv[2][4];
    #pragma unroll
    for (int i = 0; i < 2; i++) {
        #pragma unroll
        for (int r = 0; r < 4; r++) {
            float mx = acc[i][0][r];
            #pragma unroll
            for (int j = 1; j < 8; j++) mx = fmaxf(mx, acc[i][j][r]);
            #pragma unroll
            for (int m = 1; m < 16; m <<= 1) mx = fmaxf(mx, __shfl_xor(mx, m, 64));
            float sm = 0.f;
            #pragma unroll
            for (int j = 0; j < 8; j++) {
                const float p = __expf(acc[i][j][r] - mx);
                acc[i][j][r] = p;
                sm += p;
            }
            #pragma unroll
            for (int m = 1; m < 16; m <<= 1) sm += __shfl_xor(sm, m, 64);
            rinv[i][r] = 1.f / sm;
        }
    }
    __syncthreads();
    #pragma unroll
    for (int i = 0; i < 2; i++)
        #pragma unroll
        for (int j = 0; j < 8; j++)
            #pragma unroll
            for (int r = 0; r < 4; r++) {
                const int t = wv * 32 + i * 16 + quad * 4 + r;
                sPB[t * SPS + j * 16 + l16] = (u16)(__float_as_uint(acc[i][j][r]) >> 16);
            }
    __syncthreads();
    f32x4 oacc[2][2];
    #pragma unroll
    for (int i = 0; i < 2; i++)
        #pragma unroll
        for (int jd = 0; jd < 2; jd++) oacc[i][jd] = z4;
    #pragma unroll
    for (int ku = 0; ku < 4; ku++) {
        bf16x8 pf[2], vf[2];
        #pragma unroll
        for (int i = 0; i < 2; i++) pf[i] = *(const bf16x8*)&sPB[(wv * 32 + i * 16 + l16) * SPS + ku * 32 + quad * 8];
        #pragma unroll
        for (int jd = 0; jd < 2; jd++) {
            const int rv = jd * 16 + l16;
            const int b = ku * 4 + quad;
            vf[jd] = *(const bf16x8*)&sVt[rv * 128 + ((b ^ (rv & 15)) * 8)];
        }
        #pragma unroll
        for (int i = 0; i < 2; i++)
            #pragma unroll
            for (int jd = 0; jd < 2; jd++)
                oacc[i][jd] = __builtin_amdgcn_mfma_f32_16x16x32_bf16(pf[i], vf[jd], oacc[i][jd], 0, 0, 0);
    }
    #pragma unroll
    for (int i = 0; i < 2; i++)
        #pragma unroll
        for (int jd = 0; jd < 2; jd++)
            #pragma unroll
            for (int r = 0; r < 4; r++) {
                const int t = wv * 32 + i * 16 + quad * 4 + r;
                const int d = jd * 16 + l16;
                const int l = (wh * 4 + (t >> 5)) * 512 + ww * 32 + (t & 31);
                Ob[(size_t)l * 256 + h * 32 + d] = f2bf(oacc[i][jd][r] * rinv[i][r]);
            }
}

// ------------- fused wo-proj + residual + LayerNorm2 -------------
// Block = 64 rows x all 256 cols (full rows -> in-block LN).
// out[m,n] = x[m,n] + (O @ woT)[m,n] + bo[n]  (fp32, d_out)
// xn2[m,n] = LN(out[m,:])[n]                  (bf16, ws; in-place over O rows is block-private)
__global__ __launch_bounds__(256, 2) void wo_ln_k(
    const u16* __restrict__ O, const u16* __restrict__ woT, const float* __restrict__ bo,
    const float* __restrict__ x, const float* __restrict__ n2g, const float* __restrict__ n2b,
    float* __restrict__ out, u16* __restrict__ xn2) {
    __shared__ alignas(16) u16 sA[64 * 64];    // 8KB, swizzle mask 7
    __shared__ alignas(16) u16 sB[256 * 64];   // 32KB, swizzle mask 7
    __shared__ float sRed[64 * 4];             // [row][half*2 + {s,q}]
    const int tid = threadIdx.x, wv = tid >> 6, ln = tid & 63;
    const int quad = ln >> 4, l16 = ln & 15;
    const int m0 = blockIdx.x * 64;
    const int mw = (wv >> 1) * 32, nw = (wv & 1) * 128;
    const f32x4 z4 = {0.f, 0.f, 0.f, 0.f};
    f32x4 acc[2][8];
    #pragma unroll
    for (int i = 0; i < 2; i++)
        #pragma unroll
        for (int j = 0; j < 8; j++) acc[i][j] = z4;

    for (int k0 = 0; k0 < 256; k0 += 64) {
        __syncthreads();
        #pragma unroll
        for (int r = 0; r < 2; r++) {
            const int row = r * 32 + wv * 8 + (ln >> 3);
            const int kb = (ln & 7) ^ (row & 7);
            async16(O + (size_t)(m0 + row) * 256 + k0 + kb * 8, &sA[(r * 32 + wv * 8) * 64]);
        }
        #pragma unroll
        for (int r = 0; r < 8; r++) {
            const int row = r * 32 + wv * 8 + (ln >> 3);
            const int kb = (ln & 7) ^ (row & 7);
            async16(woT + (size_t)row * 256 + k0 + kb * 8, &sB[(r * 32 + wv * 8) * 64]);
        }
        __syncthreads();
        #pragma unroll
        for (int kk = 0; kk < 2; kk++) {
            bf16x8 af[2], bfr[8];
            #pragma unroll
            for (int i = 0; i < 2; i++) {
                const int ra = mw + i * 16 + l16;
                const int b = kk * 4 + quad;
                af[i] = *(const bf16x8*)&sA[ra * 64 + ((b ^ (ra & 7)) * 8)];
            }
            #pragma unroll
            for (int j = 0; j < 8; j++) {
                const int rb = nw + j * 16 + l16;
                const int b = kk * 4 + quad;
                bfr[j] = *(const bf16x8*)&sB[rb * 64 + ((b ^ (rb & 7)) * 8)];
            }
            #pragma unroll
            for (int i = 0; i < 2; i++)
                #pragma unroll
                for (int j = 0; j < 8; j++)
                    acc[i][j] = __builtin_amdgcn_mfma_f32_16x16x32_bf16(af[i], bfr[j], acc[i][j], 0, 0, 0);
        }
    }
    // epilogue: residual add + out store + row stats
    float s[2][4], q[2][4];
    #pragma unroll
    for (int i = 0; i < 2; i++)
        #pragma unroll
        for (int r = 0; r < 4; r++) { s[i][r] = 0.f; q[i][r] = 0.f; }
    #pragma unroll
    for (int j = 0; j < 8; j++) {
        const int col = nw + j * 16 + l16;
        const float bc = bo[col];
        #pragma unroll
        for (int i = 0; i < 2; i++)
            #pragma unroll
            for (int r = 0; r < 4; r++) {
                const int row = mw + i * 16 + quad * 4 + r;
                const size_t idx = (size_t)(m0 + row) * 256 + col;
                const float v = acc[i][j][r] + bc + x[idx];
                out[idx] = v;
                acc[i][j][r] = v;
                s[i][r] += v; q[i][r] += v * v;
            }
    }
    #pragma unroll
    for (int i = 0; i < 2; i++)
        #pragma unroll
        for (int r = 0; r < 4; r++) {
            #pragma unroll
            for (int m = 1; m < 16; m <<= 1) {
                s[i][r] += __shfl_xor(s[i][r], m, 64);
                q[i][r] += __shfl_xor(q[i][r], m, 64);
            }
        }
    __syncthreads();  // sA/sB reads long done; sRed fresh
    if (l16 == 0) {
        #pragma unroll
        for (int i = 0; i < 2; i++)
            #pragma unroll
            for (int r = 0; r < 4; r++) {
                const int row = mw + i * 16 + quad * 4 + r;
                sRed[row * 4 + (wv & 1) * 2]     = s[i][r];
                sRed[row * 4 + (wv & 1) * 2 + 1] = q[i][r];
            }
    }
    __syncthreads();
    float mean[2][4], rsv[2][4];
    #pragma unroll
    for (int i = 0; i < 2; i++)
        #pragma unroll
        for (int r = 0; r < 4; r++) {
            const int row = mw + i * 16 + quad * 4 + r;
            const float S = sRed[row * 4] + sRed[row * 4 + 2];
            const float Q = sRed[row * 4 + 1] + sRed[row * 4 + 3];
            const float mn = S * (1.f / 256.f);
            mean[i][r] = mn;
            rsv[i][r] = rsqrtf(Q * (1.f / 256.f) - mn * mn + LN_EPS);
        }
    #pragma unroll
    for (int j = 0; j < 8; j++) {
        const int col = nw + j * 16 + l16;
        const float g = n2g[col], bb = n2b[col];
        #pragma unroll
        for (int i = 0; i < 2; i++)
            #pragma unroll
            for (int r = 0; r < 4; r++) {
                const int row = mw + i * 16 + quad * 4 + r;
                xn2[(size_t)(m0 + row) * 256 + col] =
                    f2bf((acc[i][j][r] - mean[i][r]) * rsv[i][r] * g + bb);
            }
    }
}

// ------------- fused MLP: out[m] += gelu(xn2[m]@fc1 + b1)@fc2 + b2  (H never hits HBM) -------------
// Software-pipelined weight chunks, double-buffered; all tiles XOR-swizzled on 16B blocks.
// LDS: sA 32KB + sW0 16KB + sW1 16KB + sH 16KB = 80KB -> 2 blocks/CU.
__global__ __launch_bounds__(256, 2) void mlp_fused(
    const u16* __restrict__ Xn, const u16* __restrict__ fc1T, const u16* __restrict__ fc2T,
    const float* __restrict__ b1, const float* __restrict__ b2, float* __restrict__ Out) {
    __shared__ alignas(16) u16 sA[64 * 256];
    __shared__ alignas(16) u16 sW0[64 * 128];
    __shared__ alignas(16) u16 sW1[64 * 128];
    __shared__ alignas(16) u16 sH[64 * 128];
    const int tid = threadIdx.x, wv = tid >> 6, ln = tid & 63;
    const int quad = ln >> 4, l16 = ln & 15;
    const int m0 = blockIdx.x * 64;
    const int mw = (wv >> 1) * 32;
    const int nw1 = (wv & 1) * 64;
    const int nw2 = (wv & 1) * 128;

    auto stage_f1 = [&](int c, int kc, u16* buf) {
        #pragma unroll
        for (int rr = 0; rr < 4; rr++) {
            const int r0 = (rr * 4 + wv) * 8;
            const int row = r0 + (ln >> 3);
            const int kb = (ln & 7) ^ (row & 7);
            async16(fc1T + (size_t)(c * 128 + row) * 256 + kc * 64 + kb * 8, &buf[r0 * 64]);
        }
    };
    auto stage_f2 = [&](int c, int kc, u16* buf) {
        #pragma unroll
        for (int rr = 0; rr < 4; rr++) {
            const int r0 = (rr * 4 + wv) * 16;
            const int row = r0 + (ln >> 2);
            const int kb = (ln & 3) ^ (row & 3);
            async16(fc2T + (size_t)row * 1024 + c * 128 + kc * 32 + kb * 8, &buf[r0 * 32]);
        }
    };

    #pragma unroll
    for (int rr = 0; rr < 8; rr++) {
        const int row2 = rr * 8 + wv * 2;
        const int row = row2 + (ln >> 5);
        const int kb = (ln & 31) ^ (row & 7);
        async16(Xn + (size_t)(m0 + row) * 256 + kb * 8, &sA[row2 * 256]);
    }
    stage_f1(0, 0, sW0);

    const f32x4 z4 = {0.f, 0.f, 0.f, 0.f};
    f32x4 acc2[2][8];
    #pragma unroll
    for (int i = 0; i < 2; i++)
        #pragma unroll
        for (int j = 0; j < 8; j++) acc2[i][j] = z4;

    __syncthreads();
    for (int c = 0; c < 8; c++) {
        f32x4 acc1[2][4];
        #pragma unroll
        for (int i = 0; i < 2; i++)
            #pragma unroll
            for (int j = 0; j < 4; j++) acc1[i][j] = z4;
        #pragma unroll
        for (int kc = 0; kc < 4; kc++) {
            u16* cur = (kc & 1) ? sW1 : sW0;
            u16* nxt = (kc & 1) ? sW0 : sW1;
            if (kc < 3) stage_f1(c, kc + 1, nxt);
            #pragma unroll
            for (int kk = 0; kk < 2; kk++) {
                bf16x8 af[2], bfr[4];
                #pragma unroll
                for (int i = 0; i < 2; i++) {
                    const int ra = mw + i * 16 + l16;
                    const int b = kc * 8 + kk * 4 + quad;
                    af[i] = *(const bf16x8*)&sA[ra * 256 + ((b ^ (ra & 7)) * 8)];
                }
                #pragma unroll
                for (int j = 0; j < 4; j++) {
                    const int rb = nw1 + j * 16 + l16;
                    const int b = kk * 4 + quad;
                    bfr[j] = *(const bf16x8*)&cur[rb * 64 + ((b ^ (rb & 7)) * 8)];
                }
                #pragma unroll
                for (int i = 0; i < 2; i++)
                    #pragma unroll
                    for (int j = 0; j < 4; j++)
                        acc1[i][j] = __builtin_amdgcn_mfma_f32_16x16x32_bf16(af[i], bfr[j], acc1[i][j], 0, 0, 0);
            }
            __syncthreads();
        }
        stage_f2(c, 0, sW0);
        #pragma unroll
        for (int j = 0; j < 4; j++) {
            const float bc = b1[c * 128 + nw1 + j * 16 + l16];
            const int col = nw1 + j * 16 + l16;
            const int blk = col >> 3, off = col & 7;
            #pragma unroll
            for (int i = 0; i < 2; i++)
                #pragma unroll
                for (int r = 0; r < 4; r++) {
                    float v = acc1[i][j][r] + bc;
                    const float p = v * v;
                    const float qq = fmaf(p, -0.07135481283f, -1.5957691216f);
                    v = v / (1.f + __expf(v * qq));
                    const int row = mw + i * 16 + quad * 4 + r;
                    sH[row * 128 + ((blk ^ (row & 15)) * 8) + off] = f2bf(v);
                }
        }
        __syncthreads();
        #pragma unroll
        for (int kc = 0; kc < 4; kc++) {
            u16* cur = (kc & 1) ? sW1 : sW0;
            u16* nxt = (kc & 1) ? sW0 : sW1;
            if (kc < 3) stage_f2(c, kc + 1, nxt);
            else if (c < 7) stage_f1(c + 1, 0, nxt);
            bf16x8 pf[2], bfr[8];
            #pragma unroll
            for (int i = 0; i < 2; i++) {
                const int rp = mw + i * 16 + l16;
                const int b = kc * 4 + quad;
                pf[i] = *(const bf16x8*)&sH[rp * 128 + ((b ^ (rp & 15)) * 8)];
            }
            #pragma unroll
            for (int j = 0; j < 8; j++) {
                const int rb = nw2 + j * 16 + l16;
                bfr[j] = *(const bf16x8*)&cur[rb * 32 + ((quad ^ (rb & 3)) * 8)];
            }
            #pragma unroll
            for (int i = 0; i < 2; i++)
                #pragma unroll
                for (int j = 0; j < 8; j++)
                    acc2[i][j] = __builtin_amdgcn_mfma_f32_16x16x32_bf16(pf[i], bfr[j], acc2[i][j], 0, 0, 0);
            __syncthreads();
        }
    }
    #pragma unroll
    for (int j = 0; j < 8; j++) {
        const int col = nw2 + j * 16 + l16;
        const float bc = b2[col];
        #pragma unroll
        for (int i = 0; i < 2; i++)
            #pragma unroll
            for (int r = 0; r < 4; r++) {
                const size_t idx = (size_t)(m0 + mw + i * 16 + quad * 4 + r) * 256 + col;
                Out[idx] = acc2[i][j][r] + bc + Out[idx];
            }
    }
}

extern "C" void kernel_launch(void* const* d_in, const int* in_sizes, int n_in,
                              void* d_out, int out_size, void* d_ws, size_t ws_size,
                              hipStream_t stream) {
    const float* x    = (const float*)d_in[0];
    const float* pos  = (const float*)d_in[1];
    const float* n1g  = (const float*)d_in[2];
    const float* n1b  = (const float*)d_in[3];
    const float* wq   = (const float*)d_in[4];
    const float* bq   = (const float*)d_in[5];
    const float* wk   = (const float*)d_in[6];
    const float* bk   = (const float*)d_in[7];
    const float* wvw  = (const float*)d_in[8];
    const float* bv   = (const float*)d_in[9];
    const float* wo   = (const float*)d_in[10];
    const float* bo   = (const float*)d_in[11];
    const float* n2g  = (const float*)d_in[12];
    const float* n2b  = (const float*)d_in[13];
    const float* wfc1 = (const float*)d_in[14];
    const float* bfc1 = (const float*)d_in[15];
    const float* wfc2 = (const float*)d_in[16];
    const float* bfc2 = (const float*)d_in[17];
    const float* pw1  = (const float*)d_in[18];
    const float* pb1  = (const float*)d_in[19];
    const float* bng  = (const float*)d_in[20];
    const float* bnb  = (const float*)d_in[21];
    const float* bnm  = (const float*)d_in[22];
    const float* bnv  = (const float*)d_in[23];
    const float* pw2  = (const float*)d_in[24];
    float* out = (float*)d_out;
    u16* ws  = (u16*)d_ws;

    const size_t SZ = (size_t)32768 * 256;  // one [L,C] bf16 slot
    u16* s0   = ws;                // xn -> O -> xn2
    u16* qkv  = ws + SZ;           // packed [L][768] QKV (3 slots)
    u16* wqT  = ws + 4 * SZ;       // q,k,v transposed weights CONTIGUOUS -> fused Wt
    u16* wkT  = wqT + 65536;
    u16* wvT  = wkT + 65536;
    u16* woT  = wvT + 65536;
    u16* fc1T = woT + 65536;
    u16* fc2T = fc1T + 262144;
    u16* biasg = fc2T + 262144;    // 256*8*128*128 bf16 = 67 MB

    // [transpose x6 | LN1] in one dispatch
    prep_k<<<8960, 256, 0, stream>>>(wq, wk, wvw, wo, wfc1, wfc2,
                                     wqT, wkT, wvT, woT, fc1T, fc2T,
                                     x, n1g, n1b, s0);
    // [QKV GEMM | window bias] in one dispatch
    qkvbias_k<<<1792, 256, 0, stream>>>(s0, wqT, bq, bk, bv, qkv,
                                        pos, pw1, pb1, bng, bnb, bnm, bnv, pw2, biasg);
    attn_k<<<dim3(256, 8), 256, 0, stream>>>(qkv, biasg, s0);
    // X1 = x + O@wo + bo -> d_out (fp32)  AND  xn2 = LN2(X1) -> s0 (bf16)
    wo_ln_k<<<512, 256, 0, stream>>>(s0, woT, bo, x, n2g, n2b, out, s0);
    // fused MLP: out += gelu(xn2@fc1+b1)@fc2+b2, H stays on-chip
    mlp_fused<<<512, 256, 0, stream>>>(s0, fc1T, fc2T, bfc1, bfc2, out);
}